// Round 6
// baseline (173.931 us; speedup 1.0000x reference)
//
#include <hip/hip_runtime.h>

#define IMG 256
#define FBIG 1e10f
#define EPSA 1e-8f
#define BPAD 1e-4f
#define NSLICE 16
#define CHUNK 128
#define PXK 4
#define NBKT 1024
#define ZSCL 256.0f        // bucket = (int)(zmin*256), floor = q/256
#define ZMARG 1e-3f

// Per-face precomputed record, 64B:
// a: x1,y1, y2-y1, x2-x1   (edge0) | b: x2,y2, y0-y2, x0-x2 | c: x0,y0, y1-y0, x1-x0
// d: z0,z1,z2, area(=denom)
struct __align__(16) FRec { float4 a, b, c, d; };

__global__ __launch_bounds__(256) void precompute_kernel(
    const float* __restrict__ verts, const int* __restrict__ faces,
    FRec* __restrict__ rec_u, int* __restrict__ fid_u, int* __restrict__ bkt_u,
    unsigned int* __restrict__ cnt, unsigned int* __restrict__ hist, int V, int F)
{
#pragma clang fp contract(off)
    const int f = blockIdx.x * 256 + threadIdx.x;
    const int b = blockIdx.y;
    if (f >= F) return;
    const float* vb = verts + (size_t)b * V * 3;
    const int i0 = faces[3*f+0], i1 = faces[3*f+1], i2 = faces[3*f+2];
    const float x0 = -vb[3*i0+0], y0 = -vb[3*i0+1], z0 = vb[3*i0+2];
    const float x1 = -vb[3*i1+0], y1 = -vb[3*i1+1], z1 = vb[3*i1+2];
    const float x2 = -vb[3*i2+0], y2 = -vb[3*i2+1], z2 = vb[3*i2+2];
    const float area = (x1 - x0) * (y2 - y0) - (y1 - y0) * (x2 - x0);
    const float zmax = fmaxf(fmaxf(z0, z1), z2);
    if (area > EPSA && zmax >= 0.0f) {
        const unsigned int slot = atomicAdd(&cnt[b], 1u);
        FRec r;
        r.a = make_float4(x1, y1, y2 - y1, x2 - x1);
        r.b = make_float4(x2, y2, y0 - y2, x0 - x2);
        r.c = make_float4(x0, y0, y1 - y0, x1 - x0);
        r.d = make_float4(z0, z1, z2, area);
        rec_u[(size_t)b * F + slot] = r;
        fid_u[(size_t)b * F + slot] = f;
        const float zmin = fminf(fminf(z0, z1), z2);
        int q = (int)(zmin * ZSCL);
        q = q < 0 ? 0 : (q > NBKT - 1 ? NBKT - 1 : q);
        bkt_u[(size_t)b * F + slot] = q;
        atomicAdd(&hist[b * NBKT + q], 1u);
    }
}

__global__ __launch_bounds__(1024) void scan_kernel(
    const unsigned int* __restrict__ hist, unsigned int* __restrict__ offs)
{
    __shared__ unsigned int s[NBKT];
    const int b = blockIdx.x, t = threadIdx.x;
    const unsigned int own = hist[b * NBKT + t];
    s[t] = own;
    __syncthreads();
    for (int d = 1; d < NBKT; d <<= 1) {
        const unsigned int v = (t >= d) ? s[t - d] : 0u;
        __syncthreads();
        s[t] += v;
        __syncthreads();
    }
    offs[b * NBKT + t] = s[t] - own;   // exclusive prefix
}

__global__ __launch_bounds__(256) void scatter_kernel(
    const FRec* __restrict__ rec_u, const int* __restrict__ fid_u,
    const int* __restrict__ bkt_u, const unsigned int* __restrict__ cnt,
    unsigned int* __restrict__ offs,
    FRec* __restrict__ rec_s, int* __restrict__ fid_s, float* __restrict__ floor_s, int F)
{
    const int i = blockIdx.x * 256 + threadIdx.x;
    const int b = blockIdx.y;
    if (i >= (int)cnt[b]) return;
    const int q = bkt_u[(size_t)b * F + i];
    const unsigned int pos = atomicAdd(&offs[b * NBKT + q], 1u);
    rec_s[(size_t)b * F + pos]   = rec_u[(size_t)b * F + i];
    fid_s[(size_t)b * F + pos]   = fid_u[(size_t)b * F + i];
    floor_s[(size_t)b * F + pos] = (q == 0) ? -3e38f : (float)q * (1.0f / ZSCL);
}

__global__ __launch_bounds__(256) void raster_kernel(
    const FRec* __restrict__ rec, const int* __restrict__ fids,
    const float* __restrict__ zfloor, const unsigned int* __restrict__ cnt,
    unsigned long long* __restrict__ zpix, int F)
{
#pragma clang fp contract(off)
    __shared__ float4 s_rec[CHUNK][5];   // [0..3]=a,b,c,d  [4].x=fid bits
    __shared__ float  s_bb[4][CHUNK];    // transposed bbox
    __shared__ float  s_wmax[4];

    const int b      = blockIdx.y;
    const int slice  = blockIdx.z;
    const int region = blockIdx.x;       // 8x8 grid of 32x32-px regions
    const int rg_r = (region >> 3) * 32;
    const int rg_c = (region & 7) * 32;
    const int tid  = threadIdx.x;
    const int wv   = tid >> 6;
    const int lane = tid & 63;
    const int tile_r = rg_r + (wv >> 1) * 16;   // wave owns a 16x16 tile
    const int tile_c = rg_c + (wv & 1) * 16;
    const int col  = tile_c + (lane & 15);
    const int row0 = tile_r + (lane >> 4) * 4;  // lane owns 4 consecutive rows

    const float px = 1.0f - (2.0f * (float)col + 1.0f) / 256.0f;
    float py[PXK];
    #pragma unroll
    for (int k = 0; k < PXK; ++k)
        py[k] = 1.0f - (2.0f * (float)(row0 + k) + 1.0f) / 256.0f;

    const float px_hi = 1.0f - (2.0f * (float)tile_c + 1.0f) / 256.0f;
    const float px_lo = 1.0f - (2.0f * (float)(tile_c + 15) + 1.0f) / 256.0f;
    const float py_hi = 1.0f - (2.0f * (float)tile_r + 1.0f) / 256.0f;
    const float py_lo = 1.0f - (2.0f * (float)(tile_r + 15) + 1.0f) / 256.0f;

    const int n   = (int)cnt[b];
    const int nch = (n + CHUNK - 1) / CHUNK;
    const FRec* rbp = rec  + (size_t)b * F;
    const int*  fbp = fids + (size_t)b * F;
    const float* flp = zfloor + (size_t)b * F;

    unsigned long long best[PXK];
    float badj[PXK];
    #pragma unroll
    for (int k = 0; k < PXK; ++k) { best[k] = ~0ULL; badj[k] = FBIG; }

    for (int c = slice; c < nch; c += NSLICE) {
        __syncthreads();
        if (tid < CHUNK) {
            const int f = c * CHUNK + tid;
            if (f < n) {
                const FRec r = rbp[f];
                s_rec[tid][0] = r.a;
                s_rec[tid][1] = r.b;
                s_rec[tid][2] = r.c;
                s_rec[tid][3] = r.d;
                s_rec[tid][4] = make_float4(__int_as_float(fbp[f]), 0.f, 0.f, 0.f);
                s_bb[0][tid] = fminf(fminf(r.a.x, r.b.x), r.c.x) - BPAD;
                s_bb[1][tid] = fmaxf(fmaxf(r.a.x, r.b.x), r.c.x) + BPAD;
                s_bb[2][tid] = fminf(fminf(r.a.y, r.b.y), r.c.y) - BPAD;
                s_bb[3][tid] = fmaxf(fmaxf(r.a.y, r.b.y), r.c.y) + BPAD;
            } else {
                s_bb[0][tid] =  4e9f; s_bb[1][tid] = -4e9f;
                s_bb[2][tid] =  4e9f; s_bb[3][tid] = -4e9f;
            }
        }
        __syncthreads();

        #pragma unroll
        for (int g = 0; g < CHUNK / 64; ++g) {
            const int fl = g * 64 + lane;
            const bool ov = (s_bb[0][fl] <= px_hi) && (s_bb[1][fl] >= px_lo) &&
                            (s_bb[2][fl] <= py_hi) && (s_bb[3][fl] >= py_lo);
            unsigned long long mask = __ballot(ov);
            while (mask) {
                const int bit = (int)__builtin_ctzll(mask);
                mask &= mask - 1;
                const int idx = g * 64 + bit;            // wave-uniform
                const float4 ra = s_rec[idx][0];         // broadcast b128 reads
                const float4 rb = s_rec[idx][1];
                const float4 rc = s_rec[idx][2];
                const float4 rd = s_rec[idx][3];
                const int    fs = __float_as_int(s_rec[idx][4].x);
                const float t0 = (px - ra.x) * ra.z;
                const float t1 = (px - rb.x) * rb.z;
                const float t2 = (px - rc.x) * rc.z;
                #pragma unroll
                for (int k = 0; k < PXK; ++k) {
                    const float e0 = t0 - (py[k] - ra.y) * ra.w;
                    const float e1 = t1 - (py[k] - rb.y) * rb.w;
                    const float e2 = t2 - (py[k] - rc.y) * rc.w;
                    const float m  = fminf(fminf(e0, e1), e2);
                    const float zt = __builtin_fmaf(e2, rd.z,
                                      __builtin_fmaf(e1, rd.y, e0 * rd.x));
                    if (m >= 0.0f && zt >= -1e-4f && zt <= badj[k] * rd.w) {
                        // exact path: bit-identical to reference
                        const float w0 = e0 / rd.w;
                        const float w1 = e1 / rd.w;
                        const float w2 = e2 / rd.w;
                        const float pz = (w0 * rd.x + w1 * rd.y) + w2 * rd.z;
                        if (pz >= 0.0f && pz < FBIG) {
                            const unsigned long long cand =
                                ((unsigned long long)__float_as_uint(pz + 0.0f) << 32) |
                                (unsigned int)fs;
                            if (cand < best[k]) {
                                best[k] = cand;
                                const float bz = __uint_as_float((unsigned int)(best[k] >> 32));
                                badj[k] = bz * 1.00001f + 1e-4f;
                            }
                        }
                    }
                }
            }
        }

        // ---- feedback: publish improvements, absorb others', early-skip test ----
        float lmax = 0.0f;
        #pragma unroll
        for (int k = 0; k < PXK; ++k) {
            unsigned long long* p = &zpix[(b * IMG + row0 + k) * IMG + col];
            const unsigned long long cur = *p;           // stale-safe (monotone min)
            if (best[k] < cur) {
                atomicMin(p, best[k]);
            } else if (cur < best[k]) {
                best[k] = cur;                           // idempotent under final min
                const float bz = __uint_as_float((unsigned int)(cur >> 32));
                badj[k] = bz * 1.00001f + 1e-4f;
            }
            const unsigned int hz = (unsigned int)(best[k] >> 32);
            const float bz = (hz == 0xFFFFFFFFu) ? FBIG : __uint_as_float(hz);
            lmax = fmaxf(lmax, bz);
        }
        #pragma unroll
        for (int off = 32; off; off >>= 1)
            lmax = fmaxf(lmax, __shfl_xor(lmax, off));
        if (lane == 0) s_wmax[wv] = lmax;
        __syncthreads();
        const int cn = c + NSLICE;
        if (cn < nch) {
            const float bm = fmaxf(fmaxf(s_wmax[0], s_wmax[1]),
                                   fmaxf(s_wmax[2], s_wmax[3]));
            if (flp[cn * CHUNK] - ZMARG > bm) break;     // all remaining faces lose
        }
    }

    #pragma unroll
    for (int k = 0; k < PXK; ++k) {
        if (best[k] != ~0ULL) {
            unsigned long long* p = &zpix[(b * IMG + row0 + k) * IMG + col];
            if (best[k] < *p) atomicMin(p, best[k]);
        }
    }
}

__global__ __launch_bounds__(256) void resolve_kernel(
    const float* __restrict__ verts, const int* __restrict__ faces,
    const unsigned long long* __restrict__ zpix,
    float* __restrict__ out, int B, int V, int F)
{
#pragma clang fp contract(off)
    const int idx = blockIdx.x * 256 + threadIdx.x;
    if (idx >= B * IMG * IMG) return;
    const int b   = idx / (IMG * IMG);
    const int p   = idx - b * (IMG * IMG);
    const int row = p >> 8, col = p & 255;

    const unsigned long long v = zpix[idx];
    float p2f = -1.0f, o0 = -1.0f, o1 = -1.0f, o2 = -1.0f;
    if (v != ~0ULL) {
        const int fid = (int)(v & 0xFFFFFFFFu);
        const float* vb = verts + (size_t)b * V * 3;
        const int i0 = faces[3*fid+0], i1 = faces[3*fid+1], i2 = faces[3*fid+2];
        const float x0 = -vb[3*i0+0], y0 = -vb[3*i0+1];
        const float x1 = -vb[3*i1+0], y1 = -vb[3*i1+1];
        const float x2 = -vb[3*i2+0], y2 = -vb[3*i2+1];
        const float area = (x1 - x0) * (y2 - y0) - (y1 - y0) * (x2 - x0);
        const float px = 1.0f - (2.0f * (float)col + 1.0f) / 256.0f;
        const float py = 1.0f - (2.0f * (float)row + 1.0f) / 256.0f;
        const float e0 = (px - x1) * (y2 - y1) - (py - y1) * (x2 - x1);
        const float e1 = (px - x2) * (y0 - y2) - (py - y2) * (x0 - x2);
        const float e2 = (px - x0) * (y1 - y0) - (py - y0) * (x1 - x0);
        o0 = e0 / area; o1 = e1 / area; o2 = e2 / area;
        p2f = (float)(fid + b * F);
    }
    out[idx] = p2f;
    const size_t boff = (size_t)B * IMG * IMG + (size_t)idx * 3;
    out[boff + 0] = o0; out[boff + 1] = o1; out[boff + 2] = o2;
}

extern "C" void kernel_launch(void* const* d_in, const int* in_sizes, int n_in,
                              void* d_out, int out_size, void* d_ws, size_t ws_size,
                              hipStream_t stream) {
    const float* vertices = (const float*)d_in[0];
    const int*   faces    = (const int*)d_in[1];
    float* out = (float*)d_out;

    const int F = in_sizes[1] / 3;
    const int B = 2;
    const int V = in_sizes[0] / (3 * B);

    // ws layout
    char* w = (char*)d_ws;
    unsigned int* cnt = (unsigned int*)w;                        // B counters
    size_t off = 256;
    unsigned int* hist = (unsigned int*)(w + off); off += (size_t)B * NBKT * 4;
    unsigned int* offs = (unsigned int*)(w + off); off += (size_t)B * NBKT * 4;
    FRec* rec_u = (FRec*)(w + off);   off += (size_t)B * F * sizeof(FRec);
    int*  fid_u = (int*)(w + off);    off += (size_t)B * F * 4;
    int*  bkt_u = (int*)(w + off);    off += (size_t)B * F * 4;
    FRec* rec_s = (FRec*)(w + off);   off += (size_t)B * F * sizeof(FRec);
    int*  fid_s = (int*)(w + off);    off += (size_t)B * F * 4;
    float* floor_s = (float*)(w + off); off += (size_t)B * F * 4;
    off = (off + 255) & ~(size_t)255;
    unsigned long long* zpix = (unsigned long long*)(w + off);
    const size_t npix = (size_t)B * IMG * IMG;

    hipMemsetAsync(cnt, 0, B * sizeof(unsigned int), stream);
    hipMemsetAsync(hist, 0, (size_t)B * NBKT * 4, stream);
    hipMemsetAsync(zpix, 0xFF, npix * 8, stream);

    dim3 gpre((F + 255) / 256, B);
    precompute_kernel<<<gpre, 256, 0, stream>>>(vertices, faces, rec_u, fid_u, bkt_u,
                                                cnt, hist, V, F);
    scan_kernel<<<B, 1024, 0, stream>>>(hist, offs);
    scatter_kernel<<<gpre, 256, 0, stream>>>(rec_u, fid_u, bkt_u, cnt, offs,
                                             rec_s, fid_s, floor_s, F);

    dim3 gras(64, B, NSLICE);
    raster_kernel<<<gras, 256, 0, stream>>>(rec_s, fid_s, floor_s, cnt, zpix, F);

    dim3 gres((unsigned)((npix + 255) / 256));
    resolve_kernel<<<gres, 256, 0, stream>>>(vertices, faces, zpix, out, B, V, F);
}

// Round 7
// 130.454 us; speedup vs baseline: 1.3333x; 1.3333x over previous
//
#include <hip/hip_runtime.h>

#define IMG 256
#define FBIG 1e10f
#define EPSA 1e-8f
#define BPAD 1e-4f
#define CHUNK 128
#define PXK 4
#define NBKT 1024
#define ZSCL 256.0f        // bucket = (int)(zmin*256), floor = q/256
#define ZMARG 1e-3f

// Per-face precomputed record, 64B:
// a: x1,y1, y2-y1, x2-x1   (edge0) | b: x2,y2, y0-y2, x0-x2 | c: x0,y0, y1-y0, x1-x0
// d: z0,z1,z2, area(=denom)
struct __align__(16) FRec { float4 a, b, c, d; };

__global__ __launch_bounds__(256) void precompute_kernel(
    const float* __restrict__ verts, const int* __restrict__ faces,
    FRec* __restrict__ rec_u, int* __restrict__ fid_u, int* __restrict__ bkt_u,
    unsigned int* __restrict__ cnt, unsigned int* __restrict__ hist, int V, int F)
{
#pragma clang fp contract(off)
    const int f = blockIdx.x * 256 + threadIdx.x;
    const int b = blockIdx.y;
    if (f >= F) return;
    const float* vb = verts + (size_t)b * V * 3;
    const int i0 = faces[3*f+0], i1 = faces[3*f+1], i2 = faces[3*f+2];
    const float x0 = -vb[3*i0+0], y0 = -vb[3*i0+1], z0 = vb[3*i0+2];
    const float x1 = -vb[3*i1+0], y1 = -vb[3*i1+1], z1 = vb[3*i1+2];
    const float x2 = -vb[3*i2+0], y2 = -vb[3*i2+1], z2 = vb[3*i2+2];
    const float area = (x1 - x0) * (y2 - y0) - (y1 - y0) * (x2 - x0);
    const float zmax = fmaxf(fmaxf(z0, z1), z2);
    if (area > EPSA && zmax >= 0.0f) {
        const unsigned int slot = atomicAdd(&cnt[b], 1u);
        FRec r;
        r.a = make_float4(x1, y1, y2 - y1, x2 - x1);
        r.b = make_float4(x2, y2, y0 - y2, x0 - x2);
        r.c = make_float4(x0, y0, y1 - y0, x1 - x0);
        r.d = make_float4(z0, z1, z2, area);
        rec_u[(size_t)b * F + slot] = r;
        fid_u[(size_t)b * F + slot] = f;
        const float zmin = fminf(fminf(z0, z1), z2);
        int q = (int)(zmin * ZSCL);
        q = q < 0 ? 0 : (q > NBKT - 1 ? NBKT - 1 : q);
        bkt_u[(size_t)b * F + slot] = q;
        atomicAdd(&hist[b * NBKT + q], 1u);
    }
}

__global__ __launch_bounds__(1024) void scan_kernel(
    const unsigned int* __restrict__ hist, unsigned int* __restrict__ offs)
{
    __shared__ unsigned int s[NBKT];
    const int b = blockIdx.x, t = threadIdx.x;
    const unsigned int own = hist[b * NBKT + t];
    s[t] = own;
    __syncthreads();
    for (int d = 1; d < NBKT; d <<= 1) {
        const unsigned int v = (t >= d) ? s[t - d] : 0u;
        __syncthreads();
        s[t] += v;
        __syncthreads();
    }
    offs[b * NBKT + t] = s[t] - own;   // exclusive prefix
}

__global__ __launch_bounds__(256) void scatter_kernel(
    const FRec* __restrict__ rec_u, const int* __restrict__ fid_u,
    const int* __restrict__ bkt_u, const unsigned int* __restrict__ cnt,
    unsigned int* __restrict__ offs,
    FRec* __restrict__ rec_s, int* __restrict__ fid_s, float* __restrict__ floor_s, int F)
{
    const int i = blockIdx.x * 256 + threadIdx.x;
    const int b = blockIdx.y;
    if (i >= (int)cnt[b]) return;
    const int q = bkt_u[(size_t)b * F + i];
    const unsigned int pos = atomicAdd(&offs[b * NBKT + q], 1u);
    rec_s[(size_t)b * F + pos]   = rec_u[(size_t)b * F + i];
    fid_s[(size_t)b * F + pos]   = fid_u[(size_t)b * F + i];
    floor_s[(size_t)b * F + pos] = (q == 0) ? -3e38f : (float)q * (1.0f / ZSCL);
}

// Persistent work-queue rasterizer. Item = (chunk-major) -> (c, b, region).
__global__ __launch_bounds__(256) void raster_kernel(
    const FRec* __restrict__ rec, const int* __restrict__ fids,
    const float* __restrict__ zfloor, const unsigned int* __restrict__ cnt,
    unsigned int* __restrict__ workctr, unsigned int* __restrict__ regionBound,
    unsigned long long* __restrict__ zpix, int F)
{
#pragma clang fp contract(off)
    __shared__ float4 s_rec[CHUNK][5];   // [0..3]=a,b,c,d  [4].x=fid bits
    __shared__ float  s_bb[4][CHUNK];    // transposed bbox
    __shared__ float  s_wmax[4];
    __shared__ int    s_item, s_skip;

    const int tid  = threadIdx.x;
    const int wv   = tid >> 6;
    const int lane = tid & 63;

    const int n0 = (int)cnt[0], n1 = (int)cnt[1];
    const int nch0 = (n0 + CHUNK - 1) / CHUNK;
    const int nch1 = (n1 + CHUNK - 1) / CHUNK;
    const int nchmax = nch0 > nch1 ? nch0 : nch1;
    const int maxitems = nchmax * 128;

    for (;;) {
        __syncthreads();      // protect s_item/s_skip + LDS reuse across iterations
        if (tid == 0) {
            const int it = (int)atomicAdd(workctr, 1u);
            s_item = it;
            int skip = 0;
            if (it < maxitems) {
                const int c = it >> 7;
                const int b = (it >> 6) & 1;
                const int rg = it & 63;
                const int nch = b ? nch1 : nch0;
                if (c >= nch) skip = 1;
                else {
                    const float fl = zfloor[(size_t)b * F + c * CHUNK];
                    const unsigned int rbu = regionBound[b * 64 + rg];
                    const float bound = (rbu == 0xFFFFFFFFu) ? FBIG : __uint_as_float(rbu);
                    if (fl - ZMARG > bound) skip = 1;   // all faces in chunk lose
                }
            }
            s_skip = skip;
        }
        __syncthreads();
        const int item = s_item;
        if (item >= maxitems) break;
        if (s_skip) continue;

        const int c      = item >> 7;
        const int b      = (item >> 6) & 1;
        const int region = item & 63;
        const int n      = b ? n1 : n0;
        const FRec*  rbp = rec    + (size_t)b * F;
        const int*   fbp = fids   + (size_t)b * F;

        // ---- stage chunk ----
        if (tid < CHUNK) {
            const int f = c * CHUNK + tid;
            if (f < n) {
                const FRec r = rbp[f];
                s_rec[tid][0] = r.a;
                s_rec[tid][1] = r.b;
                s_rec[tid][2] = r.c;
                s_rec[tid][3] = r.d;
                s_rec[tid][4] = make_float4(__int_as_float(fbp[f]), 0.f, 0.f, 0.f);
                s_bb[0][tid] = fminf(fminf(r.a.x, r.b.x), r.c.x) - BPAD;
                s_bb[1][tid] = fmaxf(fmaxf(r.a.x, r.b.x), r.c.x) + BPAD;
                s_bb[2][tid] = fminf(fminf(r.a.y, r.b.y), r.c.y) - BPAD;
                s_bb[3][tid] = fmaxf(fmaxf(r.a.y, r.b.y), r.c.y) + BPAD;
            } else {
                s_bb[0][tid] =  4e9f; s_bb[1][tid] = -4e9f;
                s_bb[2][tid] =  4e9f; s_bb[3][tid] = -4e9f;
            }
        }

        // ---- per-item pixel geometry ----
        const int tile_r = (region >> 3) * 32 + (wv >> 1) * 16;
        const int tile_c = (region & 7) * 32 + (wv & 1) * 16;
        const int col  = tile_c + (lane & 15);
        const int row0 = tile_r + (lane >> 4) * 4;
        const float px = 1.0f - (2.0f * (float)col + 1.0f) / 256.0f;
        float py[PXK];
        #pragma unroll
        for (int k = 0; k < PXK; ++k)
            py[k] = 1.0f - (2.0f * (float)(row0 + k) + 1.0f) / 256.0f;
        const float px_hi = 1.0f - (2.0f * (float)tile_c + 1.0f) / 256.0f;
        const float px_lo = 1.0f - (2.0f * (float)(tile_c + 15) + 1.0f) / 256.0f;
        const float py_hi = 1.0f - (2.0f * (float)tile_r + 1.0f) / 256.0f;
        const float py_lo = 1.0f - (2.0f * (float)(tile_r + 15) + 1.0f) / 256.0f;

        // ---- init best from global zbuffer (stale-safe: monotone min) ----
        unsigned long long best[PXK], init[PXK];
        float badj[PXK];
        #pragma unroll
        for (int k = 0; k < PXK; ++k) {
            const unsigned long long cur = zpix[(b * IMG + row0 + k) * IMG + col];
            best[k] = init[k] = cur;
            if (cur != ~0ULL) {
                const float bz = __uint_as_float((unsigned int)(cur >> 32));
                badj[k] = bz * 1.00001f + 1e-4f;
            } else badj[k] = FBIG;
        }
        __syncthreads();

        // ---- test chunk ----
        #pragma unroll
        for (int g = 0; g < CHUNK / 64; ++g) {
            const int fl = g * 64 + lane;
            const bool ov = (s_bb[0][fl] <= px_hi) && (s_bb[1][fl] >= px_lo) &&
                            (s_bb[2][fl] <= py_hi) && (s_bb[3][fl] >= py_lo);
            unsigned long long mask = __ballot(ov);
            while (mask) {
                const int bit = (int)__builtin_ctzll(mask);
                mask &= mask - 1;
                const int idx = g * 64 + bit;            // wave-uniform
                const float4 ra = s_rec[idx][0];         // broadcast b128 reads
                const float4 rb = s_rec[idx][1];
                const float4 rc = s_rec[idx][2];
                const float4 rd = s_rec[idx][3];
                const int    fs = __float_as_int(s_rec[idx][4].x);
                const float t0 = (px - ra.x) * ra.z;
                const float t1 = (px - rb.x) * rb.z;
                const float t2 = (px - rc.x) * rc.z;
                #pragma unroll
                for (int k = 0; k < PXK; ++k) {
                    const float e0 = t0 - (py[k] - ra.y) * ra.w;
                    const float e1 = t1 - (py[k] - rb.y) * rb.w;
                    const float e2 = t2 - (py[k] - rc.y) * rc.w;
                    const float m  = fminf(fminf(e0, e1), e2);
                    const float zt = __builtin_fmaf(e2, rd.z,
                                      __builtin_fmaf(e1, rd.y, e0 * rd.x));
                    if (m >= 0.0f && zt >= -1e-4f && zt <= badj[k] * rd.w) {
                        // exact path: bit-identical to reference
                        const float w0 = e0 / rd.w;
                        const float w1 = e1 / rd.w;
                        const float w2 = e2 / rd.w;
                        const float pz = (w0 * rd.x + w1 * rd.y) + w2 * rd.z;
                        if (pz >= 0.0f && pz < FBIG) {
                            const unsigned long long cand =
                                ((unsigned long long)__float_as_uint(pz + 0.0f) << 32) |
                                (unsigned int)fs;
                            if (cand < best[k]) {
                                best[k] = cand;
                                const float bz = __uint_as_float((unsigned int)(best[k] >> 32));
                                badj[k] = bz * 1.00001f + 1e-4f;
                            }
                        }
                    }
                }
            }
        }

        // ---- publish improvements + update region bound ----
        float lmax = 0.0f;
        #pragma unroll
        for (int k = 0; k < PXK; ++k) {
            if (best[k] < init[k])
                atomicMin(&zpix[(b * IMG + row0 + k) * IMG + col], best[k]);
            const unsigned int hz = (unsigned int)(best[k] >> 32);
            lmax = fmaxf(lmax, (hz == 0xFFFFFFFFu) ? FBIG : __uint_as_float(hz));
        }
        #pragma unroll
        for (int off = 32; off; off >>= 1)
            lmax = fmaxf(lmax, __shfl_xor(lmax, off));
        if (lane == 0) s_wmax[wv] = lmax;
        __syncthreads();
        if (tid == 0) {
            const float bm = fmaxf(fmaxf(s_wmax[0], s_wmax[1]),
                                   fmaxf(s_wmax[2], s_wmax[3]));
            atomicMin(&regionBound[b * 64 + region], __float_as_uint(bm));
        }
    }
}

__global__ __launch_bounds__(256) void resolve_kernel(
    const float* __restrict__ verts, const int* __restrict__ faces,
    const unsigned long long* __restrict__ zpix,
    float* __restrict__ out, int B, int V, int F)
{
#pragma clang fp contract(off)
    const int idx = blockIdx.x * 256 + threadIdx.x;
    if (idx >= B * IMG * IMG) return;
    const int b   = idx / (IMG * IMG);
    const int p   = idx - b * (IMG * IMG);
    const int row = p >> 8, col = p & 255;

    const unsigned long long v = zpix[idx];
    float p2f = -1.0f, o0 = -1.0f, o1 = -1.0f, o2 = -1.0f;
    if (v != ~0ULL) {
        const int fid = (int)(v & 0xFFFFFFFFu);
        const float* vb = verts + (size_t)b * V * 3;
        const int i0 = faces[3*fid+0], i1 = faces[3*fid+1], i2 = faces[3*fid+2];
        const float x0 = -vb[3*i0+0], y0 = -vb[3*i0+1];
        const float x1 = -vb[3*i1+0], y1 = -vb[3*i1+1];
        const float x2 = -vb[3*i2+0], y2 = -vb[3*i2+1];
        const float area = (x1 - x0) * (y2 - y0) - (y1 - y0) * (x2 - x0);
        const float px = 1.0f - (2.0f * (float)col + 1.0f) / 256.0f;
        const float py = 1.0f - (2.0f * (float)row + 1.0f) / 256.0f;
        const float e0 = (px - x1) * (y2 - y1) - (py - y1) * (x2 - x1);
        const float e1 = (px - x2) * (y0 - y2) - (py - y2) * (x0 - x2);
        const float e2 = (px - x0) * (y1 - y0) - (py - y0) * (x1 - x0);
        o0 = e0 / area; o1 = e1 / area; o2 = e2 / area;
        p2f = (float)(fid + b * F);
    }
    out[idx] = p2f;
    const size_t boff = (size_t)B * IMG * IMG + (size_t)idx * 3;
    out[boff + 0] = o0; out[boff + 1] = o1; out[boff + 2] = o2;
}

extern "C" void kernel_launch(void* const* d_in, const int* in_sizes, int n_in,
                              void* d_out, int out_size, void* d_ws, size_t ws_size,
                              hipStream_t stream) {
    const float* vertices = (const float*)d_in[0];
    const int*   faces    = (const int*)d_in[1];
    float* out = (float*)d_out;

    const int F = in_sizes[1] / 3;
    const int B = 2;
    const int V = in_sizes[0] / (3 * B);

    // ws layout
    char* w = (char*)d_ws;
    // zero-init region: [0..8) cnt, [64..68) workctr, [256..) hist
    unsigned int* cnt     = (unsigned int*)w;
    unsigned int* workctr = (unsigned int*)(w + 64);
    unsigned int* hist    = (unsigned int*)(w + 256);
    size_t off = 256 + (size_t)B * NBKT * 4;
    unsigned int* offs = (unsigned int*)(w + off); off += (size_t)B * NBKT * 4;
    FRec* rec_u = (FRec*)(w + off);   off += (size_t)B * F * sizeof(FRec);
    int*  fid_u = (int*)(w + off);    off += (size_t)B * F * 4;
    int*  bkt_u = (int*)(w + off);    off += (size_t)B * F * 4;
    FRec* rec_s = (FRec*)(w + off);   off += (size_t)B * F * sizeof(FRec);
    int*  fid_s = (int*)(w + off);    off += (size_t)B * F * 4;
    float* floor_s = (float*)(w + off); off += (size_t)B * F * 4;
    off = (off + 255) & ~(size_t)255;
    // 0xFF-init region: regionBound (B*64 u32 = 512B) then zpix
    unsigned int* regionBound = (unsigned int*)(w + off);
    unsigned long long* zpix  = (unsigned long long*)(w + off + 512);
    const size_t npix = (size_t)B * IMG * IMG;

    hipMemsetAsync(w, 0, 256 + (size_t)B * NBKT * 4, stream);
    hipMemsetAsync(regionBound, 0xFF, 512 + npix * 8, stream);

    dim3 gpre((F + 255) / 256, B);
    precompute_kernel<<<gpre, 256, 0, stream>>>(vertices, faces, rec_u, fid_u, bkt_u,
                                                cnt, hist, V, F);
    scan_kernel<<<B, 1024, 0, stream>>>(hist, offs);
    scatter_kernel<<<gpre, 256, 0, stream>>>(rec_u, fid_u, bkt_u, cnt, offs,
                                             rec_s, fid_s, floor_s, F);

    raster_kernel<<<2048, 256, 0, stream>>>(rec_s, fid_s, floor_s, cnt,
                                            workctr, regionBound, zpix, F);

    dim3 gres((unsigned)((npix + 255) / 256));
    resolve_kernel<<<gres, 256, 0, stream>>>(vertices, faces, zpix, out, B, V, F);
}

// Round 8
// 111.089 us; speedup vs baseline: 1.5657x; 1.1743x over previous
//
#include <hip/hip_runtime.h>

#define IMG 256
#define FBIG 1e10f
#define EPSA 1e-8f
#define BPAD 1e-4f
#define CHUNK 128
#define PXK 4
#define NBKT 1024
#define ZSCL 256.0f        // bucket = (int)(zmin*256), floor = q/256
#define ZMARG 1e-3f

// Per-face precomputed record, 64B:
// a: x1,y1, y2-y1, x2-x1   (edge0) | b: x2,y2, y0-y2, x0-x2 | c: x0,y0, y1-y0, x1-x0
// d: z0,z1,z2, area(=denom)
struct __align__(16) FRec { float4 a, b, c, d; };

__global__ __launch_bounds__(256) void precompute_kernel(
    const float* __restrict__ verts, const int* __restrict__ faces,
    FRec* __restrict__ rec_u, int* __restrict__ fid_u, int* __restrict__ bkt_u,
    unsigned int* __restrict__ cnt, unsigned int* __restrict__ hist, int V, int F)
{
#pragma clang fp contract(off)
    const int f = blockIdx.x * 256 + threadIdx.x;
    const int b = blockIdx.y;
    if (f >= F) return;
    const float* vb = verts + (size_t)b * V * 3;
    const int i0 = faces[3*f+0], i1 = faces[3*f+1], i2 = faces[3*f+2];
    const float x0 = -vb[3*i0+0], y0 = -vb[3*i0+1], z0 = vb[3*i0+2];
    const float x1 = -vb[3*i1+0], y1 = -vb[3*i1+1], z1 = vb[3*i1+2];
    const float x2 = -vb[3*i2+0], y2 = -vb[3*i2+1], z2 = vb[3*i2+2];
    const float area = (x1 - x0) * (y2 - y0) - (y1 - y0) * (x2 - x0);
    const float zmax = fmaxf(fmaxf(z0, z1), z2);
    if (area > EPSA && zmax >= 0.0f) {
        const unsigned int slot = atomicAdd(&cnt[b], 1u);
        FRec r;
        r.a = make_float4(x1, y1, y2 - y1, x2 - x1);
        r.b = make_float4(x2, y2, y0 - y2, x0 - x2);
        r.c = make_float4(x0, y0, y1 - y0, x1 - x0);
        r.d = make_float4(z0, z1, z2, area);
        rec_u[(size_t)b * F + slot] = r;
        fid_u[(size_t)b * F + slot] = f;
        const float zmin = fminf(fminf(z0, z1), z2);
        int q = (int)(zmin * ZSCL);
        q = q < 0 ? 0 : (q > NBKT - 1 ? NBKT - 1 : q);
        bkt_u[(size_t)b * F + slot] = q;
        atomicAdd(&hist[b * NBKT + q], 1u);
    }
}

__global__ __launch_bounds__(1024) void scan_kernel(
    const unsigned int* __restrict__ hist, unsigned int* __restrict__ offs)
{
    __shared__ unsigned int s[NBKT];
    const int b = blockIdx.x, t = threadIdx.x;
    const unsigned int own = hist[b * NBKT + t];
    s[t] = own;
    __syncthreads();
    for (int d = 1; d < NBKT; d <<= 1) {
        const unsigned int v = (t >= d) ? s[t - d] : 0u;
        __syncthreads();
        s[t] += v;
        __syncthreads();
    }
    offs[b * NBKT + t] = s[t] - own;   // exclusive prefix
}

__global__ __launch_bounds__(256) void scatter_kernel(
    const FRec* __restrict__ rec_u, const int* __restrict__ fid_u,
    const int* __restrict__ bkt_u, const unsigned int* __restrict__ cnt,
    unsigned int* __restrict__ offs,
    FRec* __restrict__ rec_s, int* __restrict__ fid_s, float* __restrict__ floor_s, int F)
{
    const int i = blockIdx.x * 256 + threadIdx.x;
    const int b = blockIdx.y;
    if (i >= (int)cnt[b]) return;
    const int q = bkt_u[(size_t)b * F + i];
    const unsigned int pos = atomicAdd(&offs[b * NBKT + q], 1u);
    rec_s[(size_t)b * F + pos]   = rec_u[(size_t)b * F + i];
    fid_s[(size_t)b * F + pos]   = fid_u[(size_t)b * F + i];
    floor_s[(size_t)b * F + pos] = (q == 0) ? -3e38f : (float)q * (1.0f / ZSCL);
}

// Persistent work-queue rasterizer. Item = (chunk-major) -> (c, b, region).
__global__ __launch_bounds__(256) void raster_kernel(
    const FRec* __restrict__ rec, const int* __restrict__ fids,
    const float* __restrict__ zfloor, const unsigned int* __restrict__ cnt,
    unsigned int* __restrict__ workctr, unsigned int* __restrict__ regionBound,
    unsigned long long* __restrict__ zpix, int F)
{
#pragma clang fp contract(off)
    __shared__ float4 s_rec[CHUNK][5];   // [0..3]=a,b,c,d  [4].x=fid bits
    __shared__ float  s_bb[4][CHUNK];    // transposed bbox
    __shared__ float  s_ed[12][CHUNK];   // transposed edge data: ax,ay,ady,adx | b.. | c..
    __shared__ float  s_wmax[4];
    __shared__ int    s_item, s_skip;

    const int tid  = threadIdx.x;
    const int wv   = tid >> 6;
    const int lane = tid & 63;

    const int n0 = (int)cnt[0], n1 = (int)cnt[1];
    const int nch0 = (n0 + CHUNK - 1) / CHUNK;
    const int nch1 = (n1 + CHUNK - 1) / CHUNK;
    const int nchmax = nch0 > nch1 ? nch0 : nch1;
    const int maxitems = nchmax * 128;

    for (;;) {
        __syncthreads();      // protect s_item/s_skip + LDS reuse across iterations
        if (tid == 0) {
            const int it = (int)atomicAdd(workctr, 1u);
            s_item = it;
            int skip = 0;
            if (it < maxitems) {
                const int c = it >> 7;
                const int b = (it >> 6) & 1;
                const int rg = it & 63;
                const int nch = b ? nch1 : nch0;
                if (c >= nch) skip = 1;
                else {
                    const float fl = zfloor[(size_t)b * F + c * CHUNK];
                    const unsigned int rbu = regionBound[b * 64 + rg];
                    const float bound = (rbu == 0xFFFFFFFFu) ? FBIG : __uint_as_float(rbu);
                    if (fl - ZMARG > bound) skip = 1;   // all faces in chunk lose
                }
            }
            s_skip = skip;
        }
        __syncthreads();
        const int item = s_item;
        if (item >= maxitems) break;
        if (s_skip) continue;

        const int c      = item >> 7;
        const int b      = (item >> 6) & 1;
        const int region = item & 63;
        const int n      = b ? n1 : n0;
        const FRec*  rbp = rec  + (size_t)b * F;
        const int*   fbp = fids + (size_t)b * F;
        const float chunkfloor = zfloor[(size_t)b * F + c * CHUNK];  // min floor of chunk

        // ---- stage chunk ----
        if (tid < CHUNK) {
            const int f = c * CHUNK + tid;
            if (f < n) {
                const FRec r = rbp[f];
                s_rec[tid][0] = r.a;
                s_rec[tid][1] = r.b;
                s_rec[tid][2] = r.c;
                s_rec[tid][3] = r.d;
                s_rec[tid][4] = make_float4(__int_as_float(fbp[f]), 0.f, 0.f, 0.f);
                s_bb[0][tid] = fminf(fminf(r.a.x, r.b.x), r.c.x) - BPAD;
                s_bb[1][tid] = fmaxf(fmaxf(r.a.x, r.b.x), r.c.x) + BPAD;
                s_bb[2][tid] = fminf(fminf(r.a.y, r.b.y), r.c.y) - BPAD;
                s_bb[3][tid] = fmaxf(fmaxf(r.a.y, r.b.y), r.c.y) + BPAD;
                s_ed[0][tid] = r.a.x;  s_ed[1][tid] = r.a.y;
                s_ed[2][tid] = r.a.z;  s_ed[3][tid] = r.a.w;
                s_ed[4][tid] = r.b.x;  s_ed[5][tid] = r.b.y;
                s_ed[6][tid] = r.b.z;  s_ed[7][tid] = r.b.w;
                s_ed[8][tid] = r.c.x;  s_ed[9][tid] = r.c.y;
                s_ed[10][tid] = r.c.z; s_ed[11][tid] = r.c.w;
            } else {
                s_bb[0][tid] =  4e9f; s_bb[1][tid] = -4e9f;
                s_bb[2][tid] =  4e9f; s_bb[3][tid] = -4e9f;
            }
        }

        // ---- per-item pixel geometry ----
        const int tile_r = (region >> 3) * 32 + (wv >> 1) * 16;
        const int tile_c = (region & 7) * 32 + (wv & 1) * 16;
        const int col  = tile_c + (lane & 15);
        const int row0 = tile_r + (lane >> 4) * 4;
        const float px = 1.0f - (2.0f * (float)col + 1.0f) / 256.0f;
        float py[PXK];
        #pragma unroll
        for (int k = 0; k < PXK; ++k)
            py[k] = 1.0f - (2.0f * (float)(row0 + k) + 1.0f) / 256.0f;
        const float px_hi = 1.0f - (2.0f * (float)tile_c + 1.0f) / 256.0f;
        const float px_lo = 1.0f - (2.0f * (float)(tile_c + 15) + 1.0f) / 256.0f;
        const float py_hi = 1.0f - (2.0f * (float)tile_r + 1.0f) / 256.0f;
        const float py_lo = 1.0f - (2.0f * (float)(tile_r + 15) + 1.0f) / 256.0f;

        // ---- read current global zbuffer (z part feeds filter/skip only) ----
        unsigned long long best[PXK];
        float badj[PXK], knz[PXK];
        #pragma unroll
        for (int k = 0; k < PXK; ++k) {
            const unsigned long long cur = zpix[(b * IMG + row0 + k) * IMG + col];
            best[k] = ~0ULL;
            const unsigned int hz = (unsigned int)(cur >> 32);
            knz[k]  = (hz == 0xFFFFFFFFu) ? FBIG : __uint_as_float(hz);
            badj[k] = (hz == 0xFFFFFFFFu) ? FBIG : (knz[k] * 1.00001f + 1e-4f);
        }
        __syncthreads();

        // ---- wave-level z-skip: tile bound from just-read state ----
        float lmax = fmaxf(fmaxf(knz[0], knz[1]), fmaxf(knz[2], knz[3]));
        #pragma unroll
        for (int off = 32; off; off >>= 1)
            lmax = fmaxf(lmax, __shfl_xor(lmax, off));

        if (chunkfloor - ZMARG <= lmax) {
            // ---- test chunk ----
            #pragma unroll
            for (int g = 0; g < CHUNK / 64; ++g) {
                const int fl = g * 64 + lane;
                bool ov = (s_bb[0][fl] <= px_hi) && (s_bb[1][fl] >= px_lo) &&
                          (s_bb[2][fl] <= py_hi) && (s_bb[3][fl] >= py_lo);
                if (ov) {
                    // exact-conservative: max of each edge fn over tile rect, with
                    // reference op order (monotone rounding => no epsilon needed)
                    const float ax = s_ed[0][fl], ay = s_ed[1][fl];
                    const float ady = s_ed[2][fl], adx = s_ed[3][fl];
                    const float ea = (((ady > 0.f) ? px_hi : px_lo) - ax) * ady
                                   - (((adx > 0.f) ? py_lo : py_hi) - ay) * adx;
                    const float bx = s_ed[4][fl], by = s_ed[5][fl];
                    const float bdy = s_ed[6][fl], bdx = s_ed[7][fl];
                    const float eb = (((bdy > 0.f) ? px_hi : px_lo) - bx) * bdy
                                   - (((bdx > 0.f) ? py_lo : py_hi) - by) * bdx;
                    const float cx = s_ed[8][fl], cy = s_ed[9][fl];
                    const float cdy = s_ed[10][fl], cdx = s_ed[11][fl];
                    const float ec = (((cdy > 0.f) ? px_hi : px_lo) - cx) * cdy
                                   - (((cdx > 0.f) ? py_lo : py_hi) - cy) * cdx;
                    ov = (ea >= 0.f) && (eb >= 0.f) && (ec >= 0.f);
                }
                unsigned long long mask = __ballot(ov);
                while (mask) {
                    const int bit = (int)__builtin_ctzll(mask);
                    mask &= mask - 1;
                    const int idx = g * 64 + bit;            // wave-uniform
                    const float4 ra = s_rec[idx][0];         // broadcast b128 reads
                    const float4 rb = s_rec[idx][1];
                    const float4 rc = s_rec[idx][2];
                    const float4 rd = s_rec[idx][3];
                    const int    fs = __float_as_int(s_rec[idx][4].x);
                    const float t0 = (px - ra.x) * ra.z;
                    const float t1 = (px - rb.x) * rb.z;
                    const float t2 = (px - rc.x) * rc.z;
                    #pragma unroll
                    for (int k = 0; k < PXK; ++k) {
                        const float e0 = t0 - (py[k] - ra.y) * ra.w;
                        const float e1 = t1 - (py[k] - rb.y) * rb.w;
                        const float e2 = t2 - (py[k] - rc.y) * rc.w;
                        const float m  = fminf(fminf(e0, e1), e2);
                        const float zt = __builtin_fmaf(e2, rd.z,
                                          __builtin_fmaf(e1, rd.y, e0 * rd.x));
                        if (m >= 0.0f && zt >= -1e-4f && zt <= badj[k] * rd.w) {
                            // exact path: bit-identical to reference
                            const float w0 = e0 / rd.w;
                            const float w1 = e1 / rd.w;
                            const float w2 = e2 / rd.w;
                            const float pz = (w0 * rd.x + w1 * rd.y) + w2 * rd.z;
                            if (pz >= 0.0f && pz < FBIG) {
                                const unsigned long long cand =
                                    ((unsigned long long)__float_as_uint(pz + 0.0f) << 32) |
                                    (unsigned int)fs;
                                if (cand < best[k]) {
                                    best[k] = cand;
                                    const float bz =
                                        __uint_as_float((unsigned int)(best[k] >> 32));
                                    const float nb = bz * 1.00001f + 1e-4f;
                                    badj[k] = fminf(badj[k], nb);
                                }
                            }
                        }
                    }
                }
            }
        }

        // ---- publish candidates (unconditional atomicMin) + region bound ----
        float pmax = 0.0f;
        #pragma unroll
        for (int k = 0; k < PXK; ++k) {
            float bz = knz[k];
            if (best[k] != ~0ULL) {
                atomicMin(&zpix[(b * IMG + row0 + k) * IMG + col], best[k]);
                bz = fminf(bz, __uint_as_float((unsigned int)(best[k] >> 32)));
            }
            pmax = fmaxf(pmax, bz);
        }
        #pragma unroll
        for (int off = 32; off; off >>= 1)
            pmax = fmaxf(pmax, __shfl_xor(pmax, off));
        if (lane == 0) s_wmax[wv] = pmax;
        __syncthreads();
        if (tid == 0) {
            const float bm = fmaxf(fmaxf(s_wmax[0], s_wmax[1]),
                                   fmaxf(s_wmax[2], s_wmax[3]));
            atomicMin(&regionBound[b * 64 + region], __float_as_uint(bm));
        }
    }
}

__global__ __launch_bounds__(256) void resolve_kernel(
    const float* __restrict__ verts, const int* __restrict__ faces,
    const unsigned long long* __restrict__ zpix,
    float* __restrict__ out, int B, int V, int F)
{
#pragma clang fp contract(off)
    const int idx = blockIdx.x * 256 + threadIdx.x;
    if (idx >= B * IMG * IMG) return;
    const int b   = idx / (IMG * IMG);
    const int p   = idx - b * (IMG * IMG);
    const int row = p >> 8, col = p & 255;

    const unsigned long long v = zpix[idx];
    float p2f = -1.0f, o0 = -1.0f, o1 = -1.0f, o2 = -1.0f;
    if (v != ~0ULL) {
        const int fid = (int)(v & 0xFFFFFFFFu);
        const float* vb = verts + (size_t)b * V * 3;
        const int i0 = faces[3*fid+0], i1 = faces[3*fid+1], i2 = faces[3*fid+2];
        const float x0 = -vb[3*i0+0], y0 = -vb[3*i0+1];
        const float x1 = -vb[3*i1+0], y1 = -vb[3*i1+1];
        const float x2 = -vb[3*i2+0], y2 = -vb[3*i2+1];
        const float area = (x1 - x0) * (y2 - y0) - (y1 - y0) * (x2 - x0);
        const float px = 1.0f - (2.0f * (float)col + 1.0f) / 256.0f;
        const float py = 1.0f - (2.0f * (float)row + 1.0f) / 256.0f;
        const float e0 = (px - x1) * (y2 - y1) - (py - y1) * (x2 - x1);
        const float e1 = (px - x2) * (y0 - y2) - (py - y2) * (x0 - x2);
        const float e2 = (px - x0) * (y1 - y0) - (py - y0) * (x1 - x0);
        o0 = e0 / area; o1 = e1 / area; o2 = e2 / area;
        p2f = (float)(fid + b * F);
    }
    out[idx] = p2f;
    const size_t boff = (size_t)B * IMG * IMG + (size_t)idx * 3;
    out[boff + 0] = o0; out[boff + 1] = o1; out[boff + 2] = o2;
}

extern "C" void kernel_launch(void* const* d_in, const int* in_sizes, int n_in,
                              void* d_out, int out_size, void* d_ws, size_t ws_size,
                              hipStream_t stream) {
    const float* vertices = (const float*)d_in[0];
    const int*   faces    = (const int*)d_in[1];
    float* out = (float*)d_out;

    const int F = in_sizes[1] / 3;
    const int B = 2;
    const int V = in_sizes[0] / (3 * B);

    // ws layout
    char* w = (char*)d_ws;
    // zero-init region: [0..8) cnt, [64..68) workctr, [256..) hist
    unsigned int* cnt     = (unsigned int*)w;
    unsigned int* workctr = (unsigned int*)(w + 64);
    unsigned int* hist    = (unsigned int*)(w + 256);
    size_t off = 256 + (size_t)B * NBKT * 4;
    unsigned int* offs = (unsigned int*)(w + off); off += (size_t)B * NBKT * 4;
    FRec* rec_u = (FRec*)(w + off);   off += (size_t)B * F * sizeof(FRec);
    int*  fid_u = (int*)(w + off);    off += (size_t)B * F * 4;
    int*  bkt_u = (int*)(w + off);    off += (size_t)B * F * 4;
    FRec* rec_s = (FRec*)(w + off);   off += (size_t)B * F * sizeof(FRec);
    int*  fid_s = (int*)(w + off);    off += (size_t)B * F * 4;
    float* floor_s = (float*)(w + off); off += (size_t)B * F * 4;
    off = (off + 255) & ~(size_t)255;
    // 0xFF-init region: regionBound (B*64 u32 = 512B) then zpix
    unsigned int* regionBound = (unsigned int*)(w + off);
    unsigned long long* zpix  = (unsigned long long*)(w + off + 512);
    const size_t npix = (size_t)B * IMG * IMG;

    hipMemsetAsync(w, 0, 256 + (size_t)B * NBKT * 4, stream);
    hipMemsetAsync(regionBound, 0xFF, 512 + npix * 8, stream);

    dim3 gpre((F + 255) / 256, B);
    precompute_kernel<<<gpre, 256, 0, stream>>>(vertices, faces, rec_u, fid_u, bkt_u,
                                                cnt, hist, V, F);
    scan_kernel<<<B, 1024, 0, stream>>>(hist, offs);
    scatter_kernel<<<gpre, 256, 0, stream>>>(rec_u, fid_u, bkt_u, cnt, offs,
                                             rec_s, fid_s, floor_s, F);

    raster_kernel<<<2048, 256, 0, stream>>>(rec_s, fid_s, floor_s, cnt,
                                            workctr, regionBound, zpix, F);

    dim3 gres((unsigned)((npix + 255) / 256));
    resolve_kernel<<<gres, 256, 0, stream>>>(vertices, faces, zpix, out, B, V, F);
}

// Round 9
// 74.830 us; speedup vs baseline: 2.3244x; 1.4846x over previous
//
#include <hip/hip_runtime.h>

#define IMG 256
#define FBIG 1e10f
#define EPSA 1e-8f
#define BPAD 1e-4f
#define NBKT 1024
#define ZSCL 256.0f        // bucket = (int)(zmin*256), floor = q/256
#define ZMARG 1e-3f

// Per-face precomputed record, 64B:
// a: x1,y1, y2-y1, x2-x1   (edge0) | b: x2,y2, y0-y2, x0-x2 | c: x0,y0, y1-y0, x1-x0
// d: z0,z1,z2, area(=denom)
struct __align__(16) FRec { float4 a, b, c, d; };

__global__ __launch_bounds__(256) void precompute_kernel(
    const float* __restrict__ verts, const int* __restrict__ faces,
    FRec* __restrict__ rec_u, int* __restrict__ fid_u, int* __restrict__ bkt_u,
    unsigned int* __restrict__ cnt, unsigned int* __restrict__ hist, int V, int F)
{
#pragma clang fp contract(off)
    const int f = blockIdx.x * 256 + threadIdx.x;
    const int b = blockIdx.y;
    if (f >= F) return;
    const float* vb = verts + (size_t)b * V * 3;
    const int i0 = faces[3*f+0], i1 = faces[3*f+1], i2 = faces[3*f+2];
    const float x0 = -vb[3*i0+0], y0 = -vb[3*i0+1], z0 = vb[3*i0+2];
    const float x1 = -vb[3*i1+0], y1 = -vb[3*i1+1], z1 = vb[3*i1+2];
    const float x2 = -vb[3*i2+0], y2 = -vb[3*i2+1], z2 = vb[3*i2+2];
    const float area = (x1 - x0) * (y2 - y0) - (y1 - y0) * (x2 - x0);
    const float zmax = fmaxf(fmaxf(z0, z1), z2);
    if (area > EPSA && zmax >= 0.0f) {
        const unsigned int slot = atomicAdd(&cnt[b], 1u);
        FRec r;
        r.a = make_float4(x1, y1, y2 - y1, x2 - x1);
        r.b = make_float4(x2, y2, y0 - y2, x0 - x2);
        r.c = make_float4(x0, y0, y1 - y0, x1 - x0);
        r.d = make_float4(z0, z1, z2, area);
        rec_u[(size_t)b * F + slot] = r;
        fid_u[(size_t)b * F + slot] = f;
        const float zmin = fminf(fminf(z0, z1), z2);
        int q = (int)(zmin * ZSCL);
        q = q < 0 ? 0 : (q > NBKT - 1 ? NBKT - 1 : q);
        bkt_u[(size_t)b * F + slot] = q;
        atomicAdd(&hist[b * NBKT + q], 1u);
    }
}

__global__ __launch_bounds__(1024) void scan_kernel(
    const unsigned int* __restrict__ hist, unsigned int* __restrict__ offs)
{
    __shared__ unsigned int s[NBKT];
    const int b = blockIdx.x, t = threadIdx.x;
    const unsigned int own = hist[b * NBKT + t];
    s[t] = own;
    __syncthreads();
    for (int d = 1; d < NBKT; d <<= 1) {
        const unsigned int v = (t >= d) ? s[t - d] : 0u;
        __syncthreads();
        s[t] += v;
        __syncthreads();
    }
    offs[b * NBKT + t] = s[t] - own;   // exclusive prefix
}

__global__ __launch_bounds__(256) void scatter_kernel(
    const FRec* __restrict__ rec_u, const int* __restrict__ fid_u,
    const int* __restrict__ bkt_u, const unsigned int* __restrict__ cnt,
    unsigned int* __restrict__ offs,
    FRec* __restrict__ rec_s, int* __restrict__ fid_s, float* __restrict__ floor_s, int F)
{
    const int i = blockIdx.x * 256 + threadIdx.x;
    const int b = blockIdx.y;
    if (i >= (int)cnt[b]) return;
    const int q = bkt_u[(size_t)b * F + i];
    const unsigned int pos = atomicAdd(&offs[b * NBKT + q], 1u);
    rec_s[(size_t)b * F + pos]   = rec_u[(size_t)b * F + i];
    fid_s[(size_t)b * F + pos]   = fid_u[(size_t)b * F + i];
    floor_s[(size_t)b * F + pos] = (q == 0) ? -3e38f : (float)q * (1.0f / ZSCL);
}

#define RLF(x) __uint_as_float((unsigned int)__builtin_amdgcn_readlane(__float_as_uint(x), bit))

// One wave owns one 16x8 half-tile exclusively. No LDS, no barriers, no atomics.
__global__ __launch_bounds__(256) void raster_kernel(
    const FRec* __restrict__ rec, const int* __restrict__ fids,
    const float* __restrict__ zfloor, const unsigned int* __restrict__ cnt,
    const float* __restrict__ verts, const int* __restrict__ faces,
    float* __restrict__ out, int B, int V, int F)
{
#pragma clang fp contract(off)
    const int wv   = threadIdx.x >> 6;
    const int lane = threadIdx.x & 63;
    const int gid  = blockIdx.x * 4 + wv;     // 0..1023
    const int b    = gid >> 9;
    const int t    = gid & 511;               // 16 tile-cols x 32 tile-rows
    const int tile_c = (t & 15) * 16;
    const int tile_r = (t >> 4) * 8;
    const int col  = tile_c + (lane & 15);
    const int row0 = tile_r + (lane >> 4) * 2;   // lane owns 2 rows

    const float px = 1.0f - (2.0f * (float)col + 1.0f) / 256.0f;
    float py[2];
    py[0] = 1.0f - (2.0f * (float)(row0 + 0) + 1.0f) / 256.0f;
    py[1] = 1.0f - (2.0f * (float)(row0 + 1) + 1.0f) / 256.0f;

    // wave-uniform rect bounds (px,py decrease with pixel index)
    const float px_hi = 1.0f - (2.0f * (float)tile_c + 1.0f) / 256.0f;
    const float px_lo = 1.0f - (2.0f * (float)(tile_c + 15) + 1.0f) / 256.0f;
    const float py_hi = 1.0f - (2.0f * (float)tile_r + 1.0f) / 256.0f;
    const float py_lo = 1.0f - (2.0f * (float)(tile_r + 7) + 1.0f) / 256.0f;

    const int n = (int)cnt[b];
    const FRec*  rbp = rec    + (size_t)b * F;
    const int*   fbp = fids   + (size_t)b * F;
    const float* flp = zfloor + (size_t)b * F;

    unsigned long long best[2] = { ~0ULL, ~0ULL };
    float badj[2] = { FBIG, FBIG };
    float bound = FBIG;
    const int ngroups = (n + 63) >> 6;
    float flg = -3e38f;

    for (int g = 0; g < ngroups; ++g) {
        if (g && flg - ZMARG > bound) break;      // sorted floors: all rest lose
        const int nxt = (g + 1) << 6;
        const float fl_next = (nxt < n) ? flp[nxt] : 0.0f;   // prefetch
        const int i  = (g << 6) + lane;
        const bool val = i < n;
        const FRec r = rbp[val ? i : (n - 1)];
        const int fid = fbp[val ? i : (n - 1)];
        // bbox cull (pad covers fl-rounding acceptance outside exact triangle)
        const float xmn = fminf(fminf(r.a.x, r.b.x), r.c.x) - BPAD;
        const float xmx = fmaxf(fmaxf(r.a.x, r.b.x), r.c.x) + BPAD;
        const float ymn = fminf(fminf(r.a.y, r.b.y), r.c.y) - BPAD;
        const float ymx = fmaxf(fmaxf(r.a.y, r.b.y), r.c.y) + BPAD;
        bool ov = val && (xmn <= px_hi) && (xmx >= px_lo) &&
                         (ymn <= py_hi) && (ymx >= py_lo);
        if (ov) {
            // exact-conservative: max of each edge fn over tile rect in ref op order
            const float ea = (((r.a.z > 0.f) ? px_hi : px_lo) - r.a.x) * r.a.z
                           - (((r.a.w > 0.f) ? py_lo : py_hi) - r.a.y) * r.a.w;
            const float eb = (((r.b.z > 0.f) ? px_hi : px_lo) - r.b.x) * r.b.z
                           - (((r.b.w > 0.f) ? py_lo : py_hi) - r.b.y) * r.b.w;
            const float ec = (((r.c.z > 0.f) ? px_hi : px_lo) - r.c.x) * r.c.z
                           - (((r.c.w > 0.f) ? py_lo : py_hi) - r.c.y) * r.c.w;
            ov = (ea >= 0.f) && (eb >= 0.f) && (ec >= 0.f);
        }
        unsigned long long mask = __ballot(ov);
        while (mask) {
            const int bit = (int)__builtin_ctzll(mask);
            mask &= mask - 1;
            // broadcast survivor's record from its lane (VALU readlane -> SGPR)
            const float ax = RLF(r.a.x), ay = RLF(r.a.y), ady = RLF(r.a.z), adx = RLF(r.a.w);
            const float bx = RLF(r.b.x), by = RLF(r.b.y), bdy = RLF(r.b.z), bdx = RLF(r.b.w);
            const float cx = RLF(r.c.x), cy = RLF(r.c.y), cdy = RLF(r.c.z), cdx = RLF(r.c.w);
            const float z0 = RLF(r.d.x), z1 = RLF(r.d.y), z2 = RLF(r.d.z), area = RLF(r.d.w);
            const int   fs = __builtin_amdgcn_readlane(fid, bit);
            const float t0 = (px - ax) * ady;   // ref-identical shared terms
            const float t1 = (px - bx) * bdy;
            const float t2 = (px - cx) * cdy;
            #pragma unroll
            for (int k = 0; k < 2; ++k) {
                const float e0 = t0 - (py[k] - ay) * adx;
                const float e1 = t1 - (py[k] - by) * bdx;
                const float e2 = t2 - (py[k] - cy) * cdx;
                const float m  = fminf(fminf(e0, e1), e2);
                const float zt = __builtin_fmaf(e2, z2, __builtin_fmaf(e1, z1, e0 * z0));
                if (m >= 0.0f && zt >= -1e-4f && zt <= badj[k] * area) {
                    // exact path: bit-identical to reference
                    const float w0 = e0 / area;
                    const float w1 = e1 / area;
                    const float w2 = e2 / area;
                    const float pz = (w0 * z0 + w1 * z1) + w2 * z2;
                    if (pz >= 0.0f && pz < FBIG) {
                        const unsigned long long cand =
                            ((unsigned long long)__float_as_uint(pz + 0.0f) << 32) |
                            (unsigned int)fs;
                        if (cand < best[k]) {
                            best[k] = cand;
                            const float bz = __uint_as_float((unsigned int)(best[k] >> 32));
                            badj[k] = bz * 1.00001f + 1e-4f;
                        }
                    }
                }
            }
        }
        // ---- update wave z-bound (skip shuffle chain while any pixel empty) ----
        const bool empty = (best[0] == ~0ULL) || (best[1] == ~0ULL);
        if (__ballot(empty) == 0ULL) {
            float l = fmaxf(__uint_as_float((unsigned int)(best[0] >> 32)),
                            __uint_as_float((unsigned int)(best[1] >> 32)));
            #pragma unroll
            for (int off = 32; off; off >>= 1)
                l = fmaxf(l, __shfl_xor(l, off));
            bound = l;
        }
        flg = fl_next;
    }

    // ---- inline resolve: wave owns these pixels exclusively ----
    #pragma unroll
    for (int k = 0; k < 2; ++k) {
        const int idx = (b * IMG + row0 + k) * IMG + col;
        float p2f = -1.0f, o0 = -1.0f, o1 = -1.0f, o2 = -1.0f;
        if (best[k] != ~0ULL) {
            const int fidw = (int)(best[k] & 0xFFFFFFFFu);
            const float* vb = verts + (size_t)b * V * 3;
            const int i0 = faces[3*fidw+0], i1 = faces[3*fidw+1], i2 = faces[3*fidw+2];
            const float x0 = -vb[3*i0+0], y0 = -vb[3*i0+1];
            const float x1 = -vb[3*i1+0], y1 = -vb[3*i1+1];
            const float x2 = -vb[3*i2+0], y2 = -vb[3*i2+1];
            const float area = (x1 - x0) * (y2 - y0) - (y1 - y0) * (x2 - x0);
            const float e0 = (px - x1) * (y2 - y1) - (py[k] - y1) * (x2 - x1);
            const float e1 = (px - x2) * (y0 - y2) - (py[k] - y2) * (x0 - x2);
            const float e2 = (px - x0) * (y1 - y0) - (py[k] - y0) * (x1 - x0);
            o0 = e0 / area; o1 = e1 / area; o2 = e2 / area;
            p2f = (float)(fidw + b * F);
        }
        out[idx] = p2f;
        const size_t boff = (size_t)B * IMG * IMG + (size_t)idx * 3;
        out[boff + 0] = o0; out[boff + 1] = o1; out[boff + 2] = o2;
    }
}

extern "C" void kernel_launch(void* const* d_in, const int* in_sizes, int n_in,
                              void* d_out, int out_size, void* d_ws, size_t ws_size,
                              hipStream_t stream) {
    const float* vertices = (const float*)d_in[0];
    const int*   faces    = (const int*)d_in[1];
    float* out = (float*)d_out;

    const int F = in_sizes[1] / 3;
    const int B = 2;
    const int V = in_sizes[0] / (3 * B);

    // ws layout
    char* w = (char*)d_ws;
    unsigned int* cnt  = (unsigned int*)w;                       // [0..8) counters
    unsigned int* hist = (unsigned int*)(w + 256);
    size_t off = 256 + (size_t)B * NBKT * 4;
    unsigned int* offs = (unsigned int*)(w + off); off += (size_t)B * NBKT * 4;
    FRec* rec_u = (FRec*)(w + off);   off += (size_t)B * F * sizeof(FRec);
    int*  fid_u = (int*)(w + off);    off += (size_t)B * F * 4;
    int*  bkt_u = (int*)(w + off);    off += (size_t)B * F * 4;
    FRec* rec_s = (FRec*)(w + off);   off += (size_t)B * F * sizeof(FRec);
    int*  fid_s = (int*)(w + off);    off += (size_t)B * F * 4;
    float* floor_s = (float*)(w + off); off += (size_t)B * F * 4;

    hipMemsetAsync(w, 0, 256 + (size_t)B * NBKT * 4, stream);

    dim3 gpre((F + 255) / 256, B);
    precompute_kernel<<<gpre, 256, 0, stream>>>(vertices, faces, rec_u, fid_u, bkt_u,
                                                cnt, hist, V, F);
    scan_kernel<<<B, 1024, 0, stream>>>(hist, offs);
    scatter_kernel<<<gpre, 256, 0, stream>>>(rec_u, fid_u, bkt_u, cnt, offs,
                                             rec_s, fid_s, floor_s, F);

    raster_kernel<<<256, 256, 0, stream>>>(rec_s, fid_s, floor_s, cnt,
                                           vertices, faces, out, B, V, F);
}

// Round 10
// 58.764 us; speedup vs baseline: 2.9598x; 1.2734x over previous
//
#include <hip/hip_runtime.h>

#define IMG 256
#define FBIG 1e10f
#define EPSA 1e-8f
#define BPAD 1e-4f
#define NBKT 128
#define ZSCL 32.0f         // bucket = (int)(zmin*32), floor = q/32
#define ZMARG 1e-3f

// Per-face precomputed record, 64B:
// a: x1,y1, y2-y1, x2-x1   (edge0) | b: x2,y2, y0-y2, x0-x2 | c: x0,y0, y1-y0, x1-x0
// d: z0,z1,z2, area(=denom)
struct __align__(16) FRec { float4 a, b, c, d; };

__global__ __launch_bounds__(256) void precompute_kernel(
    const float* __restrict__ verts, const int* __restrict__ faces,
    FRec* __restrict__ rec_u, int* __restrict__ fid_u, int* __restrict__ bkt_u,
    unsigned int* __restrict__ cnt, unsigned int* __restrict__ hist, int V, int F)
{
#pragma clang fp contract(off)
    const int f = blockIdx.x * 256 + threadIdx.x;
    const int b = blockIdx.y;
    if (f >= F) return;
    const float* vb = verts + (size_t)b * V * 3;
    const int i0 = faces[3*f+0], i1 = faces[3*f+1], i2 = faces[3*f+2];
    const float x0 = -vb[3*i0+0], y0 = -vb[3*i0+1], z0 = vb[3*i0+2];
    const float x1 = -vb[3*i1+0], y1 = -vb[3*i1+1], z1 = vb[3*i1+2];
    const float x2 = -vb[3*i2+0], y2 = -vb[3*i2+1], z2 = vb[3*i2+2];
    const float area = (x1 - x0) * (y2 - y0) - (y1 - y0) * (x2 - x0);
    const float zmax = fmaxf(fmaxf(z0, z1), z2);
    if (area > EPSA && zmax >= 0.0f) {
        const unsigned int slot = atomicAdd(&cnt[b], 1u);
        FRec r;
        r.a = make_float4(x1, y1, y2 - y1, x2 - x1);
        r.b = make_float4(x2, y2, y0 - y2, x0 - x2);
        r.c = make_float4(x0, y0, y1 - y0, x1 - x0);
        r.d = make_float4(z0, z1, z2, area);
        rec_u[(size_t)b * F + slot] = r;
        fid_u[(size_t)b * F + slot] = f;
        const float zmin = fminf(fminf(z0, z1), z2);
        int q = (int)(zmin * ZSCL);
        q = q < 0 ? 0 : (q > NBKT - 1 ? NBKT - 1 : q);
        bkt_u[(size_t)b * F + slot] = q;
        atomicAdd(&hist[b * NBKT + q], 1u);
    }
}

__global__ __launch_bounds__(NBKT) void scan_kernel(
    const unsigned int* __restrict__ hist, unsigned int* __restrict__ offs)
{
    __shared__ unsigned int s[NBKT];
    const int b = blockIdx.x, t = threadIdx.x;
    const unsigned int own = hist[b * NBKT + t];
    s[t] = own;
    __syncthreads();
    for (int d = 1; d < NBKT; d <<= 1) {
        const unsigned int v = (t >= d) ? s[t - d] : 0u;
        __syncthreads();
        s[t] += v;
        __syncthreads();
    }
    offs[b * NBKT + t] = s[t] - own;   // exclusive prefix
}

__global__ __launch_bounds__(256) void scatter_kernel(
    const FRec* __restrict__ rec_u, const int* __restrict__ fid_u,
    const int* __restrict__ bkt_u, const unsigned int* __restrict__ cnt,
    unsigned int* __restrict__ offs,
    FRec* __restrict__ rec_s, int* __restrict__ fid_s, float* __restrict__ floor_s, int F)
{
    const int i = blockIdx.x * 256 + threadIdx.x;
    const int b = blockIdx.y;
    if (i >= (int)cnt[b]) return;
    const int q = bkt_u[(size_t)b * F + i];
    const unsigned int pos = atomicAdd(&offs[b * NBKT + q], 1u);
    rec_s[(size_t)b * F + pos]   = rec_u[(size_t)b * F + i];
    fid_s[(size_t)b * F + pos]   = fid_u[(size_t)b * F + i];
    floor_s[(size_t)b * F + pos] = (q == 0) ? -3e38f : (float)q * (1.0f / ZSCL);
}

#define RLF(x) __uint_as_float((unsigned int)__builtin_amdgcn_readlane(__float_as_uint(x), bit))
#define UAF(u) __uint_as_float(u)

// Block = one 16x8 tile; 4 waves slice the z-sorted face list round-robin.
// Cross-wave state: per-pixel z (u32 atomicMin, monotone) in LDS; final exact
// (z,fid) u64 merge in LDS; inline resolve by wave 0.
__global__ __launch_bounds__(256, 4) void raster_kernel(
    const FRec* __restrict__ rec, const int* __restrict__ fids,
    const float* __restrict__ zfloor, const unsigned int* __restrict__ cnt,
    const float* __restrict__ verts, const int* __restrict__ faces,
    float* __restrict__ out, int B, int V, int F)
{
#pragma clang fp contract(off)
    __shared__ unsigned int s_z[128];               // per-pixel best z bits
    __shared__ unsigned long long s_m[4][128];      // per-wave (z,fid) for merge

    const int wv   = threadIdx.x >> 6;
    const int lane = threadIdx.x & 63;
    const int blk  = blockIdx.x;                    // 0..1023
    const int b    = blk >> 9;
    const int t    = blk & 511;                     // 16 tile-cols x 32 tile-rows
    const int tile_c = (t & 15) * 16;
    const int tile_r = (t >> 4) * 8;
    const int col  = tile_c + (lane & 15);
    const int row0 = tile_r + (lane >> 4) * 2;      // lane owns 2 rows
    const int px0  = (lane & 15) + 16 * ((lane >> 4) * 2);   // tile px index, k=0 (+16 for k=1)

    if (wv == 0) { s_z[lane] = 0xFFFFFFFFu; s_z[lane + 64] = 0xFFFFFFFFu; }
    __syncthreads();

    const float px = 1.0f - (2.0f * (float)col + 1.0f) / 256.0f;
    float py[2];
    py[0] = 1.0f - (2.0f * (float)(row0 + 0) + 1.0f) / 256.0f;
    py[1] = 1.0f - (2.0f * (float)(row0 + 1) + 1.0f) / 256.0f;

    const float px_hi = 1.0f - (2.0f * (float)tile_c + 1.0f) / 256.0f;
    const float px_lo = 1.0f - (2.0f * (float)(tile_c + 15) + 1.0f) / 256.0f;
    const float py_hi = 1.0f - (2.0f * (float)tile_r + 1.0f) / 256.0f;
    const float py_lo = 1.0f - (2.0f * (float)(tile_r + 7) + 1.0f) / 256.0f;

    const int n = (int)cnt[b];
    const FRec*  rbp = rec    + (size_t)b * F;
    const int*   fbp = fids   + (size_t)b * F;
    const float* flp = zfloor + (size_t)b * F;
    const int ngroups = (n + 63) >> 6;

    unsigned long long best[2] = { ~0ULL, ~0ULL };
    float badj[2] = { FBIG, FBIG };

    int g = wv;
    FRec r; int fid = 0;
    if (g < ngroups) {
        const int i = (g << 6) + lane;
        const int ic = i < n ? i : (n - 1);
        r = rbp[ic]; fid = fbp[ic];
    }

    while (g < ngroups) {
        // ---- prefetch next slice group (2-deep pipeline) ----
        const int gn = g + 4;
        FRec r2; int fid2 = 0;
        if (gn < ngroups) {
            const int i = (gn << 6) + lane;
            const int ic = i < n ? i : (n - 1);
            r2 = rbp[ic]; fid2 = fbp[ic];
        }

        // ---- absorb cross-wave z state (stale-safe: monotone) ----
        const unsigned int zs0 = s_z[px0], zs1 = s_z[px0 + 16];
        if (zs0 != 0xFFFFFFFFu) badj[0] = fminf(badj[0], UAF(zs0) * 1.00001f + 1e-4f);
        if (zs1 != 0xFFFFFFFFu) badj[1] = fminf(badj[1], UAF(zs1) * 1.00001f + 1e-4f);
        float l = fmaxf(zs0 == 0xFFFFFFFFu ? FBIG : UAF(zs0),
                        zs1 == 0xFFFFFFFFu ? FBIG : UAF(zs1));
        #pragma unroll
        for (int off = 32; off; off >>= 1)
            l = fmaxf(l, __shfl_xor(l, off));
        if (flp[g << 6] - ZMARG > l) break;     // sorted floors: rest of slice loses

        // ---- cull ----
        const int i  = (g << 6) + lane;
        const bool val = i < n;
        const float xmn = fminf(fminf(r.a.x, r.b.x), r.c.x) - BPAD;
        const float xmx = fmaxf(fmaxf(r.a.x, r.b.x), r.c.x) + BPAD;
        const float ymn = fminf(fminf(r.a.y, r.b.y), r.c.y) - BPAD;
        const float ymx = fmaxf(fmaxf(r.a.y, r.b.y), r.c.y) + BPAD;
        bool ov = val && (xmn <= px_hi) && (xmx >= px_lo) &&
                         (ymn <= py_hi) && (ymx >= py_lo);
        if (ov) {
            // exact-conservative rect-max edge test in ref op order
            const float ea = (((r.a.z > 0.f) ? px_hi : px_lo) - r.a.x) * r.a.z
                           - (((r.a.w > 0.f) ? py_lo : py_hi) - r.a.y) * r.a.w;
            const float eb = (((r.b.z > 0.f) ? px_hi : px_lo) - r.b.x) * r.b.z
                           - (((r.b.w > 0.f) ? py_lo : py_hi) - r.b.y) * r.b.w;
            const float ec = (((r.c.z > 0.f) ? px_hi : px_lo) - r.c.x) * r.c.z
                           - (((r.c.w > 0.f) ? py_lo : py_hi) - r.c.y) * r.c.w;
            ov = (ea >= 0.f) && (eb >= 0.f) && (ec >= 0.f);
        }
        bool imp[2] = { false, false };
        unsigned long long mask = __ballot(ov);
        while (mask) {
            const int bit = (int)__builtin_ctzll(mask);
            mask &= mask - 1;
            const float ax = RLF(r.a.x), ay = RLF(r.a.y), ady = RLF(r.a.z), adx = RLF(r.a.w);
            const float bx = RLF(r.b.x), by = RLF(r.b.y), bdy = RLF(r.b.z), bdx = RLF(r.b.w);
            const float cx = RLF(r.c.x), cy = RLF(r.c.y), cdy = RLF(r.c.z), cdx = RLF(r.c.w);
            const float z0 = RLF(r.d.x), z1 = RLF(r.d.y), z2 = RLF(r.d.z), area = RLF(r.d.w);
            const int   fs = __builtin_amdgcn_readlane(fid, bit);
            const float t0 = (px - ax) * ady;   // ref-identical shared terms
            const float t1 = (px - bx) * bdy;
            const float t2 = (px - cx) * cdy;
            #pragma unroll
            for (int k = 0; k < 2; ++k) {
                const float e0 = t0 - (py[k] - ay) * adx;
                const float e1 = t1 - (py[k] - by) * bdx;
                const float e2 = t2 - (py[k] - cy) * cdx;
                const float m  = fminf(fminf(e0, e1), e2);
                const float zt = __builtin_fmaf(e2, z2, __builtin_fmaf(e1, z1, e0 * z0));
                if (m >= 0.0f && zt >= -1e-4f && zt <= badj[k] * area) {
                    // exact path: bit-identical to reference
                    const float w0 = e0 / area;
                    const float w1 = e1 / area;
                    const float w2 = e2 / area;
                    const float pz = (w0 * z0 + w1 * z1) + w2 * z2;
                    if (pz >= 0.0f && pz < FBIG) {
                        const unsigned long long cand =
                            ((unsigned long long)__float_as_uint(pz + 0.0f) << 32) |
                            (unsigned int)fs;
                        if (cand < best[k]) {
                            best[k] = cand;
                            const float bz = UAF((unsigned int)(best[k] >> 32));
                            badj[k] = fminf(badj[k], bz * 1.00001f + 1e-4f);
                            imp[k] = true;
                        }
                    }
                }
            }
        }
        // ---- publish improved z to shared per-pixel state ----
        if (imp[0]) atomicMin(&s_z[px0],      (unsigned int)(best[0] >> 32));
        if (imp[1]) atomicMin(&s_z[px0 + 16], (unsigned int)(best[1] >> 32));

        r = r2; fid = fid2; g = gn;
    }

    // ---- exact merge across the 4 waves, then inline resolve by wave 0 ----
    s_m[wv][px0]      = best[0];
    s_m[wv][px0 + 16] = best[1];
    __syncthreads();
    if (wv == 0) {
        #pragma unroll
        for (int k = 0; k < 2; ++k) {
            const int p = px0 + 16 * k;
            unsigned long long m = s_m[0][p];
            m = s_m[1][p] < m ? s_m[1][p] : m;
            m = s_m[2][p] < m ? s_m[2][p] : m;
            m = s_m[3][p] < m ? s_m[3][p] : m;

            const int idx = (b * IMG + row0 + k) * IMG + col;
            float p2f = -1.0f, o0 = -1.0f, o1 = -1.0f, o2 = -1.0f;
            if (m != ~0ULL) {
                const int fidw = (int)(m & 0xFFFFFFFFu);
                const float* vb = verts + (size_t)b * V * 3;
                const int i0 = faces[3*fidw+0], i1 = faces[3*fidw+1], i2 = faces[3*fidw+2];
                const float x0 = -vb[3*i0+0], y0 = -vb[3*i0+1];
                const float x1 = -vb[3*i1+0], y1 = -vb[3*i1+1];
                const float x2 = -vb[3*i2+0], y2 = -vb[3*i2+1];
                const float area = (x1 - x0) * (y2 - y0) - (y1 - y0) * (x2 - x0);
                const float e0 = (px - x1) * (y2 - y1) - (py[k] - y1) * (x2 - x1);
                const float e1 = (px - x2) * (y0 - y2) - (py[k] - y2) * (x0 - x2);
                const float e2 = (px - x0) * (y1 - y0) - (py[k] - y0) * (x1 - x0);
                o0 = e0 / area; o1 = e1 / area; o2 = e2 / area;
                p2f = (float)(fidw + b * F);
            }
            out[idx] = p2f;
            const size_t boff = (size_t)B * IMG * IMG + (size_t)idx * 3;
            out[boff + 0] = o0; out[boff + 1] = o1; out[boff + 2] = o2;
        }
    }
}

extern "C" void kernel_launch(void* const* d_in, const int* in_sizes, int n_in,
                              void* d_out, int out_size, void* d_ws, size_t ws_size,
                              hipStream_t stream) {
    const float* vertices = (const float*)d_in[0];
    const int*   faces    = (const int*)d_in[1];
    float* out = (float*)d_out;

    const int F = in_sizes[1] / 3;
    const int B = 2;
    const int V = in_sizes[0] / (3 * B);

    // ws layout
    char* w = (char*)d_ws;
    unsigned int* cnt  = (unsigned int*)w;                       // [0..8) counters
    unsigned int* hist = (unsigned int*)(w + 256);
    size_t off = 256 + (size_t)B * NBKT * 4;
    unsigned int* offs = (unsigned int*)(w + off); off += (size_t)B * NBKT * 4;
    FRec* rec_u = (FRec*)(w + off);   off += (size_t)B * F * sizeof(FRec);
    int*  fid_u = (int*)(w + off);    off += (size_t)B * F * 4;
    int*  bkt_u = (int*)(w + off);    off += (size_t)B * F * 4;
    FRec* rec_s = (FRec*)(w + off);   off += (size_t)B * F * sizeof(FRec);
    int*  fid_s = (int*)(w + off);    off += (size_t)B * F * 4;
    float* floor_s = (float*)(w + off); off += (size_t)B * F * 4;

    hipMemsetAsync(w, 0, 256 + (size_t)B * NBKT * 4, stream);

    dim3 gpre((F + 255) / 256, B);
    precompute_kernel<<<gpre, 256, 0, stream>>>(vertices, faces, rec_u, fid_u, bkt_u,
                                                cnt, hist, V, F);
    scan_kernel<<<B, NBKT, 0, stream>>>(hist, offs);
    scatter_kernel<<<gpre, 256, 0, stream>>>(rec_u, fid_u, bkt_u, cnt, offs,
                                             rec_s, fid_s, floor_s, F);

    raster_kernel<<<1024, 256, 0, stream>>>(rec_s, fid_s, floor_s, cnt,
                                            vertices, faces, out, B, V, F);
}

// Round 11
// 49.732 us; speedup vs baseline: 3.4974x; 1.1816x over previous
//
#include <hip/hip_runtime.h>

#define IMG 256
#define FBIG 1e10f
#define EPSA 1e-8f
#define BPAD 1e-4f
#define NBKT 128
#define ZSCL 32.0f         // bucket = (int)(zmin*32), floor = q/32
#define ZMARG 1e-3f
#define NWV 8              // waves per block (tile)

// Per-face precomputed record, 64B:
// a: x1,y1, y2-y1, x2-x1   (edge0) | b: x2,y2, y0-y2, x0-x2 | c: x0,y0, y1-y0, x1-x0
// d: z0,z1,z2, area(=denom)
struct __align__(16) FRec { float4 a, b, c, d; };

__global__ __launch_bounds__(256) void precompute_kernel(
    const float* __restrict__ verts, const int* __restrict__ faces,
    FRec* __restrict__ rec_u, int* __restrict__ fid_u, int* __restrict__ bkt_u,
    unsigned int* __restrict__ cnt, unsigned int* __restrict__ hist, int V, int F)
{
#pragma clang fp contract(off)
    const int f = blockIdx.x * 256 + threadIdx.x;
    const int b = blockIdx.y;
    if (f >= F) return;
    const float* vb = verts + (size_t)b * V * 3;
    const int i0 = faces[3*f+0], i1 = faces[3*f+1], i2 = faces[3*f+2];
    const float x0 = -vb[3*i0+0], y0 = -vb[3*i0+1], z0 = vb[3*i0+2];
    const float x1 = -vb[3*i1+0], y1 = -vb[3*i1+1], z1 = vb[3*i1+2];
    const float x2 = -vb[3*i2+0], y2 = -vb[3*i2+1], z2 = vb[3*i2+2];
    const float area = (x1 - x0) * (y2 - y0) - (y1 - y0) * (x2 - x0);
    const float zmax = fmaxf(fmaxf(z0, z1), z2);
    if (area > EPSA && zmax >= 0.0f) {
        const unsigned int slot = atomicAdd(&cnt[b], 1u);
        FRec r;
        r.a = make_float4(x1, y1, y2 - y1, x2 - x1);
        r.b = make_float4(x2, y2, y0 - y2, x0 - x2);
        r.c = make_float4(x0, y0, y1 - y0, x1 - x0);
        r.d = make_float4(z0, z1, z2, area);
        rec_u[(size_t)b * F + slot] = r;
        fid_u[(size_t)b * F + slot] = f;
        const float zmin = fminf(fminf(z0, z1), z2);
        int q = (int)(zmin * ZSCL);
        q = q < 0 ? 0 : (q > NBKT - 1 ? NBKT - 1 : q);
        const unsigned int rank = atomicAdd(&hist[b * NBKT + q], 1u);  // in-bucket rank
        bkt_u[(size_t)b * F + slot] = (q << 20) | (int)rank;
    }
}

// Scatter with block-local prefix of hist (no separate scan kernel, no atomics).
__global__ __launch_bounds__(256) void scatter_kernel(
    const FRec* __restrict__ rec_u, const int* __restrict__ fid_u,
    const int* __restrict__ bkt_u, const unsigned int* __restrict__ cnt,
    const unsigned int* __restrict__ hist,
    FRec* __restrict__ rec_s, int* __restrict__ fid_s, float* __restrict__ floor_s, int F)
{
    __shared__ unsigned int s_incl[NBKT], s_own[NBKT];
    const int tid = threadIdx.x;
    const int b   = blockIdx.y;
    if (tid < NBKT) { s_own[tid] = hist[b * NBKT + tid]; s_incl[tid] = s_own[tid]; }
    __syncthreads();
    for (int d = 1; d < NBKT; d <<= 1) {
        unsigned int v = 0;
        if (tid < NBKT && tid >= d) v = s_incl[tid - d];
        __syncthreads();
        if (tid < NBKT) s_incl[tid] += v;
        __syncthreads();
    }
    const int i = blockIdx.x * 256 + tid;
    if (i >= (int)cnt[b]) return;
    const int packed = bkt_u[(size_t)b * F + i];
    const int q    = packed >> 20;
    const int rank = packed & 0xFFFFF;
    const unsigned int pos = (s_incl[q] - s_own[q]) + (unsigned int)rank;  // excl + rank
    rec_s[(size_t)b * F + pos]   = rec_u[(size_t)b * F + i];
    fid_s[(size_t)b * F + pos]   = fid_u[(size_t)b * F + i];
    floor_s[(size_t)b * F + pos] = (q == 0) ? -3e38f : (float)q * (1.0f / ZSCL);
}

#define RLF(x) __uint_as_float((unsigned int)__builtin_amdgcn_readlane(__float_as_uint(x), bit))
#define UAF(u) __uint_as_float(u)

// Block = one 16x8 tile; 8 waves slice the z-sorted face list round-robin.
// Cross-wave state: per-pixel z (u32 atomicMin, monotone) in LDS; final exact
// (z,fid) u64 merge in LDS; inline resolve by wave 0.
__global__ __launch_bounds__(512, 8) void raster_kernel(
    const FRec* __restrict__ rec, const int* __restrict__ fids,
    const float* __restrict__ zfloor, const unsigned int* __restrict__ cnt,
    const float* __restrict__ verts, const int* __restrict__ faces,
    float* __restrict__ out, int B, int V, int F)
{
#pragma clang fp contract(off)
    __shared__ unsigned int s_z[128];                 // per-pixel best z bits
    __shared__ unsigned long long s_m[NWV][128];      // per-wave (z,fid) for merge

    const int tid  = threadIdx.x;
    const int wv   = tid >> 6;
    const int lane = tid & 63;
    const int blk  = blockIdx.x;                      // 0..1023
    const int b    = blk >> 9;
    const int t    = blk & 511;                       // 16 tile-cols x 32 tile-rows
    const int tile_c = (t & 15) * 16;
    const int tile_r = (t >> 4) * 8;
    const int col  = tile_c + (lane & 15);
    const int row0 = tile_r + (lane >> 4) * 2;        // lane owns 2 rows
    const int px0  = (lane & 15) + 16 * ((lane >> 4) * 2);

    if (tid < 128) s_z[tid] = 0xFFFFFFFFu;
    __syncthreads();

    const float px = 1.0f - (2.0f * (float)col + 1.0f) / 256.0f;
    float py[2];
    py[0] = 1.0f - (2.0f * (float)(row0 + 0) + 1.0f) / 256.0f;
    py[1] = 1.0f - (2.0f * (float)(row0 + 1) + 1.0f) / 256.0f;

    const float px_hi = 1.0f - (2.0f * (float)tile_c + 1.0f) / 256.0f;
    const float px_lo = 1.0f - (2.0f * (float)(tile_c + 15) + 1.0f) / 256.0f;
    const float py_hi = 1.0f - (2.0f * (float)tile_r + 1.0f) / 256.0f;
    const float py_lo = 1.0f - (2.0f * (float)(tile_r + 7) + 1.0f) / 256.0f;

    const int n = (int)cnt[b];
    const FRec*  rbp = rec    + (size_t)b * F;
    const int*   fbp = fids   + (size_t)b * F;
    const float* flp = zfloor + (size_t)b * F;
    const int ngroups = (n + 63) >> 6;

    unsigned long long best[2] = { ~0ULL, ~0ULL };
    float badj[2] = { FBIG, FBIG };

    for (int g = wv; g < ngroups; g += NWV) {
        // ---- absorb cross-wave z state (stale-safe: monotone) ----
        const unsigned int zs0 = s_z[px0], zs1 = s_z[px0 + 16];
        if (zs0 != 0xFFFFFFFFu) badj[0] = fminf(badj[0], UAF(zs0) * 1.00001f + 1e-4f);
        if (zs1 != 0xFFFFFFFFu) badj[1] = fminf(badj[1], UAF(zs1) * 1.00001f + 1e-4f);
        float l = fmaxf(zs0 == 0xFFFFFFFFu ? FBIG : UAF(zs0),
                        zs1 == 0xFFFFFFFFu ? FBIG : UAF(zs1));
        #pragma unroll
        for (int off = 32; off; off >>= 1)
            l = fmaxf(l, __shfl_xor(l, off));
        if (flp[g << 6] - ZMARG > l) break;     // sorted floors: rest of slice loses

        // ---- load group (lane = face) ----
        const int i  = (g << 6) + lane;
        const bool val = i < n;
        const int ic = val ? i : (n - 1);
        const FRec r = rbp[ic];
        const int fid = fbp[ic];

        // ---- cull: face-zmin vs tile bound, bbox, exact rect-max edge ----
        const float fzmin = fminf(fminf(r.d.x, r.d.y), r.d.z);
        bool ov = val && (fzmin - ZMARG <= l);
        if (ov) {
            const float xmn = fminf(fminf(r.a.x, r.b.x), r.c.x) - BPAD;
            const float xmx = fmaxf(fmaxf(r.a.x, r.b.x), r.c.x) + BPAD;
            const float ymn = fminf(fminf(r.a.y, r.b.y), r.c.y) - BPAD;
            const float ymx = fmaxf(fmaxf(r.a.y, r.b.y), r.c.y) + BPAD;
            ov = (xmn <= px_hi) && (xmx >= px_lo) && (ymn <= py_hi) && (ymx >= py_lo);
        }
        if (ov) {
            // exact-conservative rect-max edge test in ref op order
            const float ea = (((r.a.z > 0.f) ? px_hi : px_lo) - r.a.x) * r.a.z
                           - (((r.a.w > 0.f) ? py_lo : py_hi) - r.a.y) * r.a.w;
            const float eb = (((r.b.z > 0.f) ? px_hi : px_lo) - r.b.x) * r.b.z
                           - (((r.b.w > 0.f) ? py_lo : py_hi) - r.b.y) * r.b.w;
            const float ec = (((r.c.z > 0.f) ? px_hi : px_lo) - r.c.x) * r.c.z
                           - (((r.c.w > 0.f) ? py_lo : py_hi) - r.c.y) * r.c.w;
            ov = (ea >= 0.f) && (eb >= 0.f) && (ec >= 0.f);
        }
        bool imp[2] = { false, false };
        unsigned long long mask = __ballot(ov);
        while (mask) {
            const int bit = (int)__builtin_ctzll(mask);
            mask &= mask - 1;
            const float ax = RLF(r.a.x), ay = RLF(r.a.y), ady = RLF(r.a.z), adx = RLF(r.a.w);
            const float bx = RLF(r.b.x), by = RLF(r.b.y), bdy = RLF(r.b.z), bdx = RLF(r.b.w);
            const float cx = RLF(r.c.x), cy = RLF(r.c.y), cdy = RLF(r.c.z), cdx = RLF(r.c.w);
            const float z0 = RLF(r.d.x), z1 = RLF(r.d.y), z2 = RLF(r.d.z), area = RLF(r.d.w);
            const int   fs = __builtin_amdgcn_readlane(fid, bit);
            const float t0 = (px - ax) * ady;   // ref-identical shared terms
            const float t1 = (px - bx) * bdy;
            const float t2 = (px - cx) * cdy;
            #pragma unroll
            for (int k = 0; k < 2; ++k) {
                const float e0 = t0 - (py[k] - ay) * adx;
                const float e1 = t1 - (py[k] - by) * bdx;
                const float e2 = t2 - (py[k] - cy) * cdx;
                const float m  = fminf(fminf(e0, e1), e2);
                const float zt = __builtin_fmaf(e2, z2, __builtin_fmaf(e1, z1, e0 * z0));
                if (m >= 0.0f && zt >= -1e-4f && zt <= badj[k] * area) {
                    // exact path: bit-identical to reference
                    const float w0 = e0 / area;
                    const float w1 = e1 / area;
                    const float w2 = e2 / area;
                    const float pz = (w0 * z0 + w1 * z1) + w2 * z2;
                    if (pz >= 0.0f && pz < FBIG) {
                        const unsigned long long cand =
                            ((unsigned long long)__float_as_uint(pz + 0.0f) << 32) |
                            (unsigned int)fs;
                        if (cand < best[k]) {
                            best[k] = cand;
                            const float bz = UAF((unsigned int)(best[k] >> 32));
                            badj[k] = fminf(badj[k], bz * 1.00001f + 1e-4f);
                            imp[k] = true;
                        }
                    }
                }
            }
        }
        // ---- publish improved z to shared per-pixel state ----
        if (imp[0]) atomicMin(&s_z[px0],      (unsigned int)(best[0] >> 32));
        if (imp[1]) atomicMin(&s_z[px0 + 16], (unsigned int)(best[1] >> 32));
    }

    // ---- exact merge across the 8 waves, then inline resolve by wave 0 ----
    s_m[wv][px0]      = best[0];
    s_m[wv][px0 + 16] = best[1];
    __syncthreads();
    if (wv == 0) {
        #pragma unroll
        for (int k = 0; k < 2; ++k) {
            const int p = px0 + 16 * k;
            unsigned long long m = s_m[0][p];
            #pragma unroll
            for (int j = 1; j < NWV; ++j) m = s_m[j][p] < m ? s_m[j][p] : m;

            const int idx = (b * IMG + row0 + k) * IMG + col;
            float p2f = -1.0f, o0 = -1.0f, o1 = -1.0f, o2 = -1.0f;
            if (m != ~0ULL) {
                const int fidw = (int)(m & 0xFFFFFFFFu);
                const float* vb = verts + (size_t)b * V * 3;
                const int i0 = faces[3*fidw+0], i1 = faces[3*fidw+1], i2 = faces[3*fidw+2];
                const float x0 = -vb[3*i0+0], y0 = -vb[3*i0+1];
                const float x1 = -vb[3*i1+0], y1 = -vb[3*i1+1];
                const float x2 = -vb[3*i2+0], y2 = -vb[3*i2+1];
                const float area = (x1 - x0) * (y2 - y0) - (y1 - y0) * (x2 - x0);
                const float e0 = (px - x1) * (y2 - y1) - (py[k] - y1) * (x2 - x1);
                const float e1 = (px - x2) * (y0 - y2) - (py[k] - y2) * (x0 - x2);
                const float e2 = (px - x0) * (y1 - y0) - (py[k] - y0) * (x1 - x0);
                o0 = e0 / area; o1 = e1 / area; o2 = e2 / area;
                p2f = (float)(fidw + b * F);
            }
            out[idx] = p2f;
            const size_t boff = (size_t)B * IMG * IMG + (size_t)idx * 3;
            out[boff + 0] = o0; out[boff + 1] = o1; out[boff + 2] = o2;
        }
    }
}

extern "C" void kernel_launch(void* const* d_in, const int* in_sizes, int n_in,
                              void* d_out, int out_size, void* d_ws, size_t ws_size,
                              hipStream_t stream) {
    const float* vertices = (const float*)d_in[0];
    const int*   faces    = (const int*)d_in[1];
    float* out = (float*)d_out;

    const int F = in_sizes[1] / 3;
    const int B = 2;
    const int V = in_sizes[0] / (3 * B);

    // ws layout
    char* w = (char*)d_ws;
    unsigned int* cnt  = (unsigned int*)w;                       // [0..8) counters
    unsigned int* hist = (unsigned int*)(w + 256);
    size_t off = 256 + (size_t)B * NBKT * 4;
    FRec* rec_u = (FRec*)(w + off);   off += (size_t)B * F * sizeof(FRec);
    int*  fid_u = (int*)(w + off);    off += (size_t)B * F * 4;
    int*  bkt_u = (int*)(w + off);    off += (size_t)B * F * 4;
    FRec* rec_s = (FRec*)(w + off);   off += (size_t)B * F * sizeof(FRec);
    int*  fid_s = (int*)(w + off);    off += (size_t)B * F * 4;
    float* floor_s = (float*)(w + off); off += (size_t)B * F * 4;

    hipMemsetAsync(w, 0, 256 + (size_t)B * NBKT * 4, stream);

    dim3 gpre((F + 255) / 256, B);
    precompute_kernel<<<gpre, 256, 0, stream>>>(vertices, faces, rec_u, fid_u, bkt_u,
                                                cnt, hist, V, F);
    scatter_kernel<<<gpre, 256, 0, stream>>>(rec_u, fid_u, bkt_u, cnt, hist,
                                             rec_s, fid_s, floor_s, F);

    raster_kernel<<<1024, 512, 0, stream>>>(rec_s, fid_s, floor_s, cnt,
                                            vertices, faces, out, B, V, F);
}

// Round 12
// 46.554 us; speedup vs baseline: 3.7361x; 1.0683x over previous
//
#include <hip/hip_runtime.h>

#define IMG 256
#define FBIG 1e10f
#define EPSA 1e-8f
#define BPAD 1e-4f
#define NBKT 128
#define ZSCL 32.0f         // bucket = (int)(zmin*32), floor = q/32
#define ZMARG 1e-3f
#define NWV 8              // waves per block (tile)

// Full per-face record, 64B:
// a: x1,y1, y2-y1, x2-x1   (edge0) | b: x2,y2, y0-y2, x0-x2 | c: x0,y0, y1-y0, x1-x0
// d: z0,z1,z2, area(=denom)
struct __align__(16) FRec { float4 a, b, c, d; };
// Cull record, 8B: quantized-outward pixel bbox + exact zmin
struct __align__(8) CRec { unsigned int bb; float zmin; };

__global__ __launch_bounds__(256) void precompute_kernel(
    const float* __restrict__ verts, const int* __restrict__ faces,
    FRec* __restrict__ rec_u, CRec* __restrict__ crec_u, int* __restrict__ fid_u,
    int* __restrict__ bkt_u,
    unsigned int* __restrict__ cnt, unsigned int* __restrict__ hist, int V, int F)
{
#pragma clang fp contract(off)
    const int f = blockIdx.x * 256 + threadIdx.x;
    const int b = blockIdx.y;
    if (f >= F) return;
    const float* vb = verts + (size_t)b * V * 3;
    const int i0 = faces[3*f+0], i1 = faces[3*f+1], i2 = faces[3*f+2];
    const float x0 = -vb[3*i0+0], y0 = -vb[3*i0+1], z0 = vb[3*i0+2];
    const float x1 = -vb[3*i1+0], y1 = -vb[3*i1+1], z1 = vb[3*i1+2];
    const float x2 = -vb[3*i2+0], y2 = -vb[3*i2+1], z2 = vb[3*i2+2];
    const float area = (x1 - x0) * (y2 - y0) - (y1 - y0) * (x2 - x0);
    const float zmax = fmaxf(fmaxf(z0, z1), z2);
    if (area > EPSA && zmax >= 0.0f) {
        const unsigned int slot = atomicAdd(&cnt[b], 1u);
        FRec r;
        r.a = make_float4(x1, y1, y2 - y1, x2 - x1);
        r.b = make_float4(x2, y2, y0 - y2, x0 - x2);
        r.c = make_float4(x0, y0, y1 - y0, x1 - x0);
        r.d = make_float4(z0, z1, z2, area);
        rec_u[(size_t)b * F + slot] = r;
        fid_u[(size_t)b * F + slot] = f;
        // quantized-outward pixel bbox (col = (1-px)*128-0.5, px decreasing in col)
        const float xmn = fminf(fminf(x0, x1), x2) - BPAD;
        const float xmx = fmaxf(fmaxf(x0, x1), x2) + BPAD;
        const float ymn = fminf(fminf(y0, y1), y2) - BPAD;
        const float ymx = fmaxf(fmaxf(y0, y1), y2) + BPAD;
        int cmin = (int)floorf((1.0f - xmx) * 128.0f - 0.5f);
        int cmax = (int)ceilf ((1.0f - xmn) * 128.0f - 0.5f);
        int rmin = (int)floorf((1.0f - ymx) * 128.0f - 0.5f);
        int rmax = (int)ceilf ((1.0f - ymn) * 128.0f - 0.5f);
        cmin = min(max(cmin, 0), 255); cmax = min(max(cmax, 0), 255);
        rmin = min(max(rmin, 0), 255); rmax = min(max(rmax, 0), 255);
        CRec cr;
        cr.bb = (unsigned int)cmin | ((unsigned int)cmax << 8) |
                ((unsigned int)rmin << 16) | ((unsigned int)rmax << 24);
        cr.zmin = fminf(fminf(z0, z1), z2);
        crec_u[(size_t)b * F + slot] = cr;
        int q = (int)(cr.zmin * ZSCL);
        q = q < 0 ? 0 : (q > NBKT - 1 ? NBKT - 1 : q);
        const unsigned int rank = atomicAdd(&hist[b * NBKT + q], 1u);  // in-bucket rank
        bkt_u[(size_t)b * F + slot] = (q << 20) | (int)rank;
    }
}

// Scatter with block-local prefix of hist (no separate scan kernel, no atomics).
__global__ __launch_bounds__(256) void scatter_kernel(
    const FRec* __restrict__ rec_u, const CRec* __restrict__ crec_u,
    const int* __restrict__ fid_u,
    const int* __restrict__ bkt_u, const unsigned int* __restrict__ cnt,
    const unsigned int* __restrict__ hist,
    FRec* __restrict__ rec_s, CRec* __restrict__ crec_s, int* __restrict__ fid_s,
    float* __restrict__ floor_s, int F)
{
    __shared__ unsigned int s_incl[NBKT], s_own[NBKT];
    const int tid = threadIdx.x;
    const int b   = blockIdx.y;
    if (tid < NBKT) { s_own[tid] = hist[b * NBKT + tid]; s_incl[tid] = s_own[tid]; }
    __syncthreads();
    for (int d = 1; d < NBKT; d <<= 1) {
        unsigned int v = 0;
        if (tid < NBKT && tid >= d) v = s_incl[tid - d];
        __syncthreads();
        if (tid < NBKT) s_incl[tid] += v;
        __syncthreads();
    }
    const int i = blockIdx.x * 256 + tid;
    if (i >= (int)cnt[b]) return;
    const int packed = bkt_u[(size_t)b * F + i];
    const int q    = packed >> 20;
    const int rank = packed & 0xFFFFF;
    const unsigned int pos = (s_incl[q] - s_own[q]) + (unsigned int)rank;  // excl + rank
    rec_s[(size_t)b * F + pos]   = rec_u[(size_t)b * F + i];
    crec_s[(size_t)b * F + pos]  = crec_u[(size_t)b * F + i];
    fid_s[(size_t)b * F + pos]   = fid_u[(size_t)b * F + i];
    floor_s[(size_t)b * F + pos] = (q == 0) ? -3e38f : (float)q * (1.0f / ZSCL);
}

#define RLF(x) __uint_as_float((unsigned int)__builtin_amdgcn_readlane(__float_as_uint(x), bit))
#define UAF(u) __uint_as_float(u)

// Block = one 16x8 tile; 8 waves slice the z-sorted face list round-robin.
// Two-level cull: 8B CRec (int bbox + zmin) -> survivors gather 64B FRec.
__global__ __launch_bounds__(512, 8) void raster_kernel(
    const FRec* __restrict__ rec, const CRec* __restrict__ crec,
    const int* __restrict__ fids,
    const float* __restrict__ zfloor, const unsigned int* __restrict__ cnt,
    const float* __restrict__ verts, const int* __restrict__ faces,
    float* __restrict__ out, int B, int V, int F)
{
#pragma clang fp contract(off)
    __shared__ unsigned int s_z[128];                 // per-pixel best z bits
    __shared__ unsigned long long s_m[NWV][128];      // per-wave (z,fid) for merge

    const int tid  = threadIdx.x;
    const int wv   = tid >> 6;
    const int lane = tid & 63;
    const int blk  = blockIdx.x;                      // 0..1023
    const int b    = blk >> 9;
    const int t    = blk & 511;                       // 16 tile-cols x 32 tile-rows
    const int tile_c = (t & 15) * 16;
    const int tile_r = (t >> 4) * 8;
    const int col  = tile_c + (lane & 15);
    const int row0 = tile_r + (lane >> 4) * 2;        // lane owns 2 rows
    const int px0  = (lane & 15) + 16 * ((lane >> 4) * 2);

    if (tid < 128) s_z[tid] = 0xFFFFFFFFu;
    __syncthreads();

    const float px = 1.0f - (2.0f * (float)col + 1.0f) / 256.0f;
    float py[2];
    py[0] = 1.0f - (2.0f * (float)(row0 + 0) + 1.0f) / 256.0f;
    py[1] = 1.0f - (2.0f * (float)(row0 + 1) + 1.0f) / 256.0f;

    const float px_hi = 1.0f - (2.0f * (float)tile_c + 1.0f) / 256.0f;
    const float px_lo = 1.0f - (2.0f * (float)(tile_c + 15) + 1.0f) / 256.0f;
    const float py_hi = 1.0f - (2.0f * (float)tile_r + 1.0f) / 256.0f;
    const float py_lo = 1.0f - (2.0f * (float)(tile_r + 7) + 1.0f) / 256.0f;

    const int n = (int)cnt[b];
    const FRec*  rbp = rec    + (size_t)b * F;
    const CRec*  crp = crec   + (size_t)b * F;
    const int*   fbp = fids   + (size_t)b * F;
    const float* flp = zfloor + (size_t)b * F;
    const int ngroups = (n + 63) >> 6;

    unsigned long long best[2] = { ~0ULL, ~0ULL };
    float badj[2] = { FBIG, FBIG };

    for (int g = wv; g < ngroups; g += NWV) {
        // ---- absorb cross-wave z state (stale-safe: monotone) ----
        const unsigned int zs0 = s_z[px0], zs1 = s_z[px0 + 16];
        if (zs0 != 0xFFFFFFFFu) badj[0] = fminf(badj[0], UAF(zs0) * 1.00001f + 1e-4f);
        if (zs1 != 0xFFFFFFFFu) badj[1] = fminf(badj[1], UAF(zs1) * 1.00001f + 1e-4f);
        float l = fmaxf(zs0 == 0xFFFFFFFFu ? FBIG : UAF(zs0),
                        zs1 == 0xFFFFFFFFu ? FBIG : UAF(zs1));
        #pragma unroll
        for (int off = 32; off; off >>= 1)
            l = fmaxf(l, __shfl_xor(l, off));
        if (flp[g << 6] - ZMARG > l) break;     // sorted floors: rest of slice loses

        // ---- level-1 cull: 8B record (int bbox + zmin) ----
        const int i  = (g << 6) + lane;
        const bool val = i < n;
        const int ic = val ? i : (n - 1);
        const CRec cr = crp[ic];
        bool ov = val && (cr.zmin - ZMARG <= l) &&
                  ((int)(cr.bb & 255u)         <= tile_c + 15) &&
                  ((int)((cr.bb >> 8)  & 255u) >= tile_c)      &&
                  ((int)((cr.bb >> 16) & 255u) <= tile_r + 7)  &&
                  ((int)((cr.bb >> 24) & 255u) >= tile_r);

        // ---- level-2: survivors gather full record + exact rect-max edge test ----
        FRec r; int fid = 0;
        if (ov) {
            r = rbp[ic]; fid = fbp[ic];
            const float ea = (((r.a.z > 0.f) ? px_hi : px_lo) - r.a.x) * r.a.z
                           - (((r.a.w > 0.f) ? py_lo : py_hi) - r.a.y) * r.a.w;
            const float eb = (((r.b.z > 0.f) ? px_hi : px_lo) - r.b.x) * r.b.z
                           - (((r.b.w > 0.f) ? py_lo : py_hi) - r.b.y) * r.b.w;
            const float ec = (((r.c.z > 0.f) ? px_hi : px_lo) - r.c.x) * r.c.z
                           - (((r.c.w > 0.f) ? py_lo : py_hi) - r.c.y) * r.c.w;
            ov = (ea >= 0.f) && (eb >= 0.f) && (ec >= 0.f);
        }
        bool imp[2] = { false, false };
        unsigned long long mask = __ballot(ov);
        while (mask) {
            const int bit = (int)__builtin_ctzll(mask);
            mask &= mask - 1;
            const float ax = RLF(r.a.x), ay = RLF(r.a.y), ady = RLF(r.a.z), adx = RLF(r.a.w);
            const float bx = RLF(r.b.x), by = RLF(r.b.y), bdy = RLF(r.b.z), bdx = RLF(r.b.w);
            const float cx = RLF(r.c.x), cy = RLF(r.c.y), cdy = RLF(r.c.z), cdx = RLF(r.c.w);
            const float z0 = RLF(r.d.x), z1 = RLF(r.d.y), z2 = RLF(r.d.z), area = RLF(r.d.w);
            const int   fs = __builtin_amdgcn_readlane(fid, bit);
            const float t0 = (px - ax) * ady;   // ref-identical shared terms
            const float t1 = (px - bx) * bdy;
            const float t2 = (px - cx) * cdy;
            #pragma unroll
            for (int k = 0; k < 2; ++k) {
                const float e0 = t0 - (py[k] - ay) * adx;
                const float e1 = t1 - (py[k] - by) * bdx;
                const float e2 = t2 - (py[k] - cy) * cdx;
                const float m  = fminf(fminf(e0, e1), e2);
                const float zt = __builtin_fmaf(e2, z2, __builtin_fmaf(e1, z1, e0 * z0));
                if (m >= 0.0f && zt >= -1e-4f && zt <= badj[k] * area) {
                    // exact path: bit-identical to reference
                    const float w0 = e0 / area;
                    const float w1 = e1 / area;
                    const float w2 = e2 / area;
                    const float pz = (w0 * z0 + w1 * z1) + w2 * z2;
                    if (pz >= 0.0f && pz < FBIG) {
                        const unsigned long long cand =
                            ((unsigned long long)__float_as_uint(pz + 0.0f) << 32) |
                            (unsigned int)fs;
                        if (cand < best[k]) {
                            best[k] = cand;
                            const float bz = UAF((unsigned int)(best[k] >> 32));
                            badj[k] = fminf(badj[k], bz * 1.00001f + 1e-4f);
                            imp[k] = true;
                        }
                    }
                }
            }
        }
        // ---- publish improved z to shared per-pixel state ----
        if (imp[0]) atomicMin(&s_z[px0],      (unsigned int)(best[0] >> 32));
        if (imp[1]) atomicMin(&s_z[px0 + 16], (unsigned int)(best[1] >> 32));
    }

    // ---- exact merge across the 8 waves, then inline resolve by wave 0 ----
    s_m[wv][px0]      = best[0];
    s_m[wv][px0 + 16] = best[1];
    __syncthreads();
    if (wv == 0) {
        #pragma unroll
        for (int k = 0; k < 2; ++k) {
            const int p = px0 + 16 * k;
            unsigned long long m = s_m[0][p];
            #pragma unroll
            for (int j = 1; j < NWV; ++j) m = s_m[j][p] < m ? s_m[j][p] : m;

            const int idx = (b * IMG + row0 + k) * IMG + col;
            float p2f = -1.0f, o0 = -1.0f, o1 = -1.0f, o2 = -1.0f;
            if (m != ~0ULL) {
                const int fidw = (int)(m & 0xFFFFFFFFu);
                const float* vb = verts + (size_t)b * V * 3;
                const int i0 = faces[3*fidw+0], i1 = faces[3*fidw+1], i2 = faces[3*fidw+2];
                const float x0 = -vb[3*i0+0], y0 = -vb[3*i0+1];
                const float x1 = -vb[3*i1+0], y1 = -vb[3*i1+1];
                const float x2 = -vb[3*i2+0], y2 = -vb[3*i2+1];
                const float area = (x1 - x0) * (y2 - y0) - (y1 - y0) * (x2 - x0);
                const float e0 = (px - x1) * (y2 - y1) - (py[k] - y1) * (x2 - x1);
                const float e1 = (px - x2) * (y0 - y2) - (py[k] - y2) * (x0 - x2);
                const float e2 = (px - x0) * (y1 - y0) - (py[k] - y0) * (x1 - x0);
                o0 = e0 / area; o1 = e1 / area; o2 = e2 / area;
                p2f = (float)(fidw + b * F);
            }
            out[idx] = p2f;
            const size_t boff = (size_t)B * IMG * IMG + (size_t)idx * 3;
            out[boff + 0] = o0; out[boff + 1] = o1; out[boff + 2] = o2;
        }
    }
}

extern "C" void kernel_launch(void* const* d_in, const int* in_sizes, int n_in,
                              void* d_out, int out_size, void* d_ws, size_t ws_size,
                              hipStream_t stream) {
    const float* vertices = (const float*)d_in[0];
    const int*   faces    = (const int*)d_in[1];
    float* out = (float*)d_out;

    const int F = in_sizes[1] / 3;
    const int B = 2;
    const int V = in_sizes[0] / (3 * B);

    // ws layout
    char* w = (char*)d_ws;
    unsigned int* cnt  = (unsigned int*)w;                       // [0..8) counters
    unsigned int* hist = (unsigned int*)(w + 256);
    size_t off = 256 + (size_t)B * NBKT * 4;
    FRec* rec_u = (FRec*)(w + off);   off += (size_t)B * F * sizeof(FRec);
    CRec* crec_u = (CRec*)(w + off);  off += (size_t)B * F * sizeof(CRec);
    int*  fid_u = (int*)(w + off);    off += (size_t)B * F * 4;
    int*  bkt_u = (int*)(w + off);    off += (size_t)B * F * 4;
    FRec* rec_s = (FRec*)(w + off);   off += (size_t)B * F * sizeof(FRec);
    CRec* crec_s = (CRec*)(w + off);  off += (size_t)B * F * sizeof(CRec);
    int*  fid_s = (int*)(w + off);    off += (size_t)B * F * 4;
    float* floor_s = (float*)(w + off); off += (size_t)B * F * 4;

    hipMemsetAsync(w, 0, 256 + (size_t)B * NBKT * 4, stream);

    dim3 gpre((F + 255) / 256, B);
    precompute_kernel<<<gpre, 256, 0, stream>>>(vertices, faces, rec_u, crec_u, fid_u,
                                                bkt_u, cnt, hist, V, F);
    scatter_kernel<<<gpre, 256, 0, stream>>>(rec_u, crec_u, fid_u, bkt_u, cnt, hist,
                                             rec_s, crec_s, fid_s, floor_s, F);

    raster_kernel<<<1024, 512, 0, stream>>>(rec_s, crec_s, fid_s, floor_s, cnt,
                                            vertices, faces, out, B, V, F);
}